// Round 1
// baseline (7142.273 us; speedup 1.0000x reference)
//
#include <hip/hip_runtime.h>
#include <math.h>

#define Bc 4
#define Nn 4000
// padded N*N so float4 tile reads past col 3999 stay in-buffer
#define NP (16000000 + 4096)

// ---------------------------------------------------------------------------
// K1: t_lhs[b,t] = sum_{n,f} x*U1[n] ; t_rhs[b,t] = sum_{n,f,g} x*U2[g,n]*U3[g]
// one thread per (b,n); wave-reduce then atomicAdd
__global__ __launch_bounds__(256) void k1_trhs(
    const float* __restrict__ x, const float* __restrict__ U1,
    const float* __restrict__ U2, const float* __restrict__ U3,
    float* __restrict__ tl, float* __restrict__ tr) {
  int b = blockIdx.y;
  int n = blockIdx.x * 256 + threadIdx.x;
  float xs[16];
#pragma unroll
  for (int t = 0; t < 16; ++t) xs[t] = 0.f;
  float c1 = 0.f, c2 = 0.f;
  if (n < Nn) {
    const float* xr = x + ((size_t)b * Nn + n) * 256;
    for (int f = 0; f < 16; ++f) {
#pragma unroll
      for (int q = 0; q < 4; ++q) {
        float4 v = *(const float4*)(xr + f * 16 + q * 4);
        xs[q * 4 + 0] += v.x; xs[q * 4 + 1] += v.y;
        xs[q * 4 + 2] += v.z; xs[q * 4 + 3] += v.w;
      }
    }
    c1 = U1[n];
#pragma unroll
    for (int g = 0; g < 16; ++g) c2 += U2[g * Nn + n] * U3[g];
  }
  int lane = threadIdx.x & 63;
#pragma unroll
  for (int t = 0; t < 16; ++t) {
    float v1 = c1 * xs[t];
    float v2 = c2 * xs[t];
#pragma unroll
    for (int off = 32; off > 0; off >>= 1) {
      v1 += __shfl_down(v1, off, 64);
      v2 += __shfl_down(v2, off, 64);
    }
    if (lane == 0) {
      atomicAdd(&tl[b * 16 + t], v1);
      atomicAdd(&tr[b * 16 + t], v2);
    }
  }
}

// ---------------------------------------------------------------------------
// K2: temporal attention E = softmax(Ve @ sigmoid(t_lhs outer t_rhs + be)),
// output Ecol[b,s] = sum_t E[b,t,s].  one block per batch.
__global__ __launch_bounds__(256) void k2_eattn(
    const float* __restrict__ tl, const float* __restrict__ tr,
    const float* __restrict__ be, const float* __restrict__ Ve,
    float* __restrict__ ecol) {
  int b = blockIdx.x;
  int tid = threadIdx.x;
  __shared__ float sig[256];
  __shared__ float Em[256];
  int s = tid >> 4, r = tid & 15;
  float z = tl[b * 16 + s] * tr[b * 16 + r] + be[s * 16 + r];
  sig[s * 16 + r] = 1.0f / (1.0f + __expf(-z));
  __syncthreads();
  float e = 0.f;
#pragma unroll
  for (int ss = 0; ss < 16; ++ss) e += Ve[s * 16 + ss] * sig[ss * 16 + r];
  Em[s * 16 + r] = e;  // E_raw[t=s][r]
  __syncthreads();
  if (tid < 16) {  // softmax over r, row tid
    float m = -1e30f;
#pragma unroll
    for (int rr = 0; rr < 16; ++rr) m = fmaxf(m, Em[tid * 16 + rr]);
    float ssum = 0.f;
    float ex[16];
#pragma unroll
    for (int rr = 0; rr < 16; ++rr) { ex[rr] = __expf(Em[tid * 16 + rr] - m); ssum += ex[rr]; }
    float inv = 1.0f / ssum;
#pragma unroll
    for (int rr = 0; rr < 16; ++rr) Em[tid * 16 + rr] = ex[rr] * inv;
  }
  __syncthreads();
  if (tid < 16) {
    float c = 0.f;
#pragma unroll
    for (int tt = 0; tt < 16; ++tt) c += Em[tt * 16 + tid];
    ecol[b * 16 + tid] = c;
  }
}

// ---------------------------------------------------------------------------
// K3: per (b,n) small contractions over the 256-element x row:
//   xts  = sum_s Ecol[s] x[..s]        (T-attended, t-summed x)
//   slhs = sum_t x W1[t]
//   srhs[g] = sum_k W2[g,k] (sum_t x[k,t] W3[t])
//   base = time_out + time_b + residual
__global__ __launch_bounds__(256) void k3_pern(
    const float* __restrict__ x, const float* __restrict__ ecol,
    const float* __restrict__ W1, const float* __restrict__ W2,
    const float* __restrict__ W3, const float* __restrict__ time_w,
    const float* __restrict__ time_b,
    float* __restrict__ xts, float* __restrict__ slhs,
    float* __restrict__ srhs, float* __restrict__ base) {
  __shared__ float tws[4096];
  __shared__ float W1s[16], W3s[16], Ecs[16], tbs[16], W2s[256];
  int tid = threadIdx.x;
  int b = blockIdx.y;
  for (int i = tid; i < 4096; i += 256) tws[i] = time_w[i];
  W2s[tid] = W2[tid & 255];
  if (tid < 16) {
    W1s[tid] = W1[tid]; W3s[tid] = W3[tid];
    Ecs[tid] = ecol[b * 16 + tid]; tbs[tid] = time_b[tid];
  }
  __syncthreads();
  int n = blockIdx.x * 256 + tid;
  if (n >= Nn) return;
  const float* xr = x + ((size_t)b * Nn + n) * 256;
  float xtsv[16], slv[16], xw3[16], to[16], resid[16];
#pragma unroll
  for (int i = 0; i < 16; ++i) { xtsv[i] = 0; slv[i] = 0; xw3[i] = 0; to[i] = 0; }
  for (int f = 0; f < 16; ++f) {
    float xf[16];
#pragma unroll
    for (int q = 0; q < 4; ++q) {
      float4 v = *(const float4*)(xr + f * 16 + q * 4);
      xf[q * 4 + 0] = v.x; xf[q * 4 + 1] = v.y; xf[q * 4 + 2] = v.z; xf[q * 4 + 3] = v.w;
    }
    float a = 0, c = 0, d = 0;
#pragma unroll
    for (int t2 = 0; t2 < 16; ++t2) {
      a += Ecs[t2] * xf[t2];
      c += W1s[t2] * xf[t2];
      d += W3s[t2] * xf[t2];
    }
    xtsv[f] = a; slv[f] = c; xw3[f] = d; resid[f] = xf[15];
#pragma unroll
    for (int o = 0; o < 16; ++o) {
      float acc = 0;
#pragma unroll
      for (int t2 = 0; t2 < 16; ++t2) acc += tws[o * 256 + f * 16 + t2] * xf[t2];
      to[o] += acc;
    }
  }
  size_t o16 = ((size_t)b * Nn + n) * 16;
#pragma unroll
  for (int g = 0; g < 16; ++g) {
    float acc = 0;
#pragma unroll
    for (int k2 = 0; k2 < 16; ++k2) acc += W2s[g * 16 + k2] * xw3[k2];
    srhs[o16 + g] = acc;
  }
#pragma unroll
  for (int i = 0; i < 16; ++i) {
    xts[o16 + i] = xtsv[i];
    slhs[o16 + i] = slv[i];
    base[o16 + i] = to[i] + tbs[i] + resid[i];
  }
}

// ---------------------------------------------------------------------------
// GEMM1: P[m,k] = sigmoid( sum_f slhs[b,m,f]*srhs[b,k,f] + bs[m,k] ), 64x64 tiles
__global__ __launch_bounds__(256) void gemm1_P(
    const float* __restrict__ slhs, const float* __restrict__ srhs,
    const float* __restrict__ bsm, float* __restrict__ P, int b) {
  __shared__ float As[64][17];
  __shared__ float Bs2[64][17];
  int tid = threadIdx.x;
  int m0 = blockIdx.y * 64, k0 = blockIdx.x * 64;
  int lr = tid >> 2, lq = (tid & 3) << 2;
  {
    int gm = m0 + lr; if (gm > Nn - 1) gm = Nn - 1;
    float4 v = *(const float4*)(slhs + ((size_t)b * Nn + gm) * 16 + lq);
    As[lr][lq + 0] = v.x; As[lr][lq + 1] = v.y; As[lr][lq + 2] = v.z; As[lr][lq + 3] = v.w;
    int gk = k0 + lr; if (gk > Nn - 1) gk = Nn - 1;
    float4 w = *(const float4*)(srhs + ((size_t)b * Nn + gk) * 16 + lq);
    Bs2[lr][lq + 0] = w.x; Bs2[lr][lq + 1] = w.y; Bs2[lr][lq + 2] = w.z; Bs2[lr][lq + 3] = w.w;
  }
  __syncthreads();
  int tx = tid & 15, ty = tid >> 4;  // tx -> k cols, ty -> m rows
  float acc[4][4] = {};
#pragma unroll
  for (int f = 0; f < 16; ++f) {
    float a4[4], b4[4];
#pragma unroll
    for (int i = 0; i < 4; ++i) a4[i] = As[ty * 4 + i][f];
#pragma unroll
    for (int j = 0; j < 4; ++j) b4[j] = Bs2[tx * 4 + j][f];
#pragma unroll
    for (int i = 0; i < 4; ++i)
#pragma unroll
      for (int j = 0; j < 4; ++j) acc[i][j] += a4[i] * b4[j];
  }
#pragma unroll
  for (int i = 0; i < 4; ++i) {
    int m = m0 + ty * 4 + i;
    if (m >= Nn) continue;
    int k = k0 + tx * 4;
    size_t rowoff = (size_t)m * Nn;
    if (k + 3 < Nn) {
      float4 bv = *(const float4*)(bsm + rowoff + k);
      float4 o;
      o.x = 1.f / (1.f + __expf(-(acc[i][0] + bv.x)));
      o.y = 1.f / (1.f + __expf(-(acc[i][1] + bv.y)));
      o.z = 1.f / (1.f + __expf(-(acc[i][2] + bv.z)));
      o.w = 1.f / (1.f + __expf(-(acc[i][3] + bv.w)));
      *(float4*)(P + rowoff + k) = o;
    } else {
      for (int j = 0; j < 4; ++j)
        if (k + j < Nn) {
          float z = acc[i][j] + bsm[rowoff + k + j];
          P[rowoff + k + j] = 1.f / (1.f + __expf(-z));
        }
    }
  }
}

// ---------------------------------------------------------------------------
// GEMM2 (the 512-GFLOP core): SP[n,k] = sum_m Vs[n,m] * P[m,k]
// 128x128 tile, BK=16, 256 thr, 8x8 microtile, A transposed in LDS.
__global__ __launch_bounds__(256) void gemm2_spre(
    const float* __restrict__ Vs, const float* __restrict__ P,
    float* __restrict__ SP) {
  __shared__ float As[16][128];
  __shared__ float Bs2[16][128];
  int tid = threadIdx.x;
  int row0 = blockIdx.y * 128, col0 = blockIdx.x * 128;
  int tx = tid & 15, ty = tid >> 4;
  int aRow = tid >> 2, aCol = (tid & 3) << 2;
  int bRow = tid >> 5, bCol = (tid & 31) << 2;
  float acc[8][8] = {};
  for (int m0 = 0; m0 < Nn; m0 += 16) {
#pragma unroll
    for (int p = 0; p < 2; ++p) {
      int r = row0 + aRow + p * 64; if (r > Nn - 1) r = Nn - 1;
      float4 v = *(const float4*)(Vs + (size_t)r * Nn + m0 + aCol);
      As[aCol + 0][aRow + p * 64] = v.x;
      As[aCol + 1][aRow + p * 64] = v.y;
      As[aCol + 2][aRow + p * 64] = v.z;
      As[aCol + 3][aRow + p * 64] = v.w;
      int rb = m0 + bRow + p * 8;
      *(float4*)(&Bs2[bRow + p * 8][bCol]) =
          *(const float4*)(P + (size_t)rb * Nn + col0 + bCol);  // P padded
    }
    __syncthreads();
#pragma unroll
    for (int kk = 0; kk < 16; ++kk) {
      float af[8], bf[8];
      *(float4*)(af) = *(const float4*)(&As[kk][ty * 4]);
      *(float4*)(af + 4) = *(const float4*)(&As[kk][64 + ty * 4]);
      *(float4*)(bf) = *(const float4*)(&Bs2[kk][tx * 4]);
      *(float4*)(bf + 4) = *(const float4*)(&Bs2[kk][64 + tx * 4]);
#pragma unroll
      for (int i = 0; i < 8; ++i)
#pragma unroll
        for (int j = 0; j < 8; ++j) acc[i][j] += af[i] * bf[j];
    }
    __syncthreads();
  }
#pragma unroll
  for (int i = 0; i < 8; ++i) {
    int r = row0 + ((i < 4) ? (ty * 4 + i) : (64 + ty * 4 + i - 4));
    if (r >= Nn) continue;
#pragma unroll
    for (int jh = 0; jh < 2; ++jh) {
      int c = col0 + jh * 64 + tx * 4;
      if (c + 3 < Nn) {
        float4 v = make_float4(acc[i][jh * 4 + 0], acc[i][jh * 4 + 1],
                               acc[i][jh * 4 + 2], acc[i][jh * 4 + 3]);
        *(float4*)(SP + (size_t)r * Nn + c) = v;
      } else {
        for (int j = 0; j < 4; ++j)
          if (c + j < Nn) SP[(size_t)r * Nn + c + j] = acc[i][jh * 4 + j];
      }
    }
  }
}

// ---------------------------------------------------------------------------
// rowstat: per-row max and 1/sum(exp) over SP row (softmax stats). block/row.
__global__ __launch_bounds__(256) void rowstat(
    const float* __restrict__ SP, float* __restrict__ rmx, float* __restrict__ rinv) {
  int n = blockIdx.x;
  int tid = threadIdx.x;
  const float* row = SP + (size_t)n * Nn;
  __shared__ float red[256];
  float m = -3.0e38f;
  for (int k = tid; k < Nn; k += 256) m = fmaxf(m, row[k]);
  red[tid] = m;
  __syncthreads();
  for (int s2 = 128; s2 > 0; s2 >>= 1) {
    if (tid < s2) red[tid] = fmaxf(red[tid], red[tid + s2]);
    __syncthreads();
  }
  float rm = red[0];
  __syncthreads();
  float ssum = 0.f;
  for (int k = tid; k < Nn; k += 256) ssum += __expf(row[k] - rm);
  red[tid] = ssum;
  __syncthreads();
  for (int s2 = 128; s2 > 0; s2 >>= 1) {
    if (tid < s2) red[tid] += red[tid + s2];
    __syncthreads();
  }
  if (tid == 0) { rmx[n] = rm; rinv[n] = 1.0f / red[0]; }
}

// ---------------------------------------------------------------------------
// txsum0: ts0[b,n,f] = sum_k softmax(SP)[n,k] * xts[b,k,f]  (exp on the fly)
__global__ __launch_bounds__(256) void txsum0_k(
    const float* __restrict__ SP, const float* __restrict__ xts,
    const float* __restrict__ rmx, const float* __restrict__ rinv,
    float* __restrict__ ts0, int b) {
  __shared__ float Ws[16][65];
  __shared__ float Xs[64][17];
  int tid = threadIdx.x;
  int n0 = blockIdx.x * 16;
  int r = tid >> 4, f = tid & 15;
  int xr = tid >> 2, xc = (tid & 3) << 2;
  float rm = rmx[n0 + r], ri = rinv[n0 + r];
  float acc = 0.f;
  for (int k0 = 0; k0 < Nn; k0 += 64) {
    int gk4 = k0 + f * 4;
    {
      float4 v = *(const float4*)(SP + (size_t)(n0 + r) * Nn + gk4);  // pad-safe
      Ws[r][f * 4 + 0] = (gk4 + 0 < Nn) ? __expf(v.x - rm) * ri : 0.f;
      Ws[r][f * 4 + 1] = (gk4 + 1 < Nn) ? __expf(v.y - rm) * ri : 0.f;
      Ws[r][f * 4 + 2] = (gk4 + 2 < Nn) ? __expf(v.z - rm) * ri : 0.f;
      Ws[r][f * 4 + 3] = (gk4 + 3 < Nn) ? __expf(v.w - rm) * ri : 0.f;
    }
    int gk = k0 + xr;
    if (gk < Nn) {
      float4 v = *(const float4*)(xts + ((size_t)b * Nn + gk) * 16 + xc);
      Xs[xr][xc + 0] = v.x; Xs[xr][xc + 1] = v.y; Xs[xr][xc + 2] = v.z; Xs[xr][xc + 3] = v.w;
    } else {
      Xs[xr][xc + 0] = 0.f; Xs[xr][xc + 1] = 0.f; Xs[xr][xc + 2] = 0.f; Xs[xr][xc + 3] = 0.f;
    }
    __syncthreads();
#pragma unroll
    for (int kk = 0; kk < 64; ++kk) acc += Ws[r][kk] * Xs[kk][f];
    __syncthreads();
  }
  ts0[((size_t)b * Nn + n0 + r) * 16 + f] = acc;
}

// ---------------------------------------------------------------------------
// cheb: Cout[b,n,f] = scale * sum_m A[n,m]*Bin[b,m,f] - (C0 ? C0[b,n,f] : 0)
__global__ __launch_bounds__(256) void cheb_k(
    const float* __restrict__ A, const float* __restrict__ Bin,
    const float* __restrict__ C0, float* __restrict__ Cout, float scale) {
  __shared__ float Ws[16][65];
  __shared__ float Xs[64][17];
  int tid = threadIdx.x;
  int b = blockIdx.y;
  int n0 = blockIdx.x * 16;
  int r = tid >> 4, f = tid & 15;
  int xr = tid >> 2, xc = (tid & 3) << 2;
  float acc = 0.f;
  for (int k0 = 0; k0 < Nn; k0 += 64) {
    int gk4 = k0 + f * 4;
    if (gk4 + 3 < Nn) {
      float4 v = *(const float4*)(A + (size_t)(n0 + r) * Nn + gk4);
      Ws[r][f * 4 + 0] = v.x; Ws[r][f * 4 + 1] = v.y;
      Ws[r][f * 4 + 2] = v.z; Ws[r][f * 4 + 3] = v.w;
    } else {
      for (int q = 0; q < 4; ++q)
        Ws[r][f * 4 + q] = (gk4 + q < Nn) ? A[(size_t)(n0 + r) * Nn + gk4 + q] : 0.f;
    }
    int gk = k0 + xr;
    if (gk < Nn) {
      float4 v = *(const float4*)(Bin + ((size_t)b * Nn + gk) * 16 + xc);
      Xs[xr][xc + 0] = v.x; Xs[xr][xc + 1] = v.y; Xs[xr][xc + 2] = v.z; Xs[xr][xc + 3] = v.w;
    } else {
      Xs[xr][xc + 0] = 0.f; Xs[xr][xc + 1] = 0.f; Xs[xr][xc + 2] = 0.f; Xs[xr][xc + 3] = 0.f;
    }
    __syncthreads();
#pragma unroll
    for (int kk = 0; kk < 64; ++kk) acc += Ws[r][kk] * Xs[kk][f];
    __syncthreads();
  }
  size_t idx = ((size_t)b * Nn + n0 + r) * 16 + f;
  float v = scale * acc;
  if (C0) v -= C0[idx];
  Cout[idx] = v;
}

// ---------------------------------------------------------------------------
// K_y: y = (1/16)*sum_k sum_f tsk[n,f]*cw[k,f,o] + base ; accumulate LN stats
__global__ __launch_bounds__(256) void ky_k(
    const float* __restrict__ ts0, const float* __restrict__ ts1,
    const float* __restrict__ ts2, const float* __restrict__ cw,
    const float* __restrict__ base, float* __restrict__ ybuf,
    float* __restrict__ lnacc) {
  __shared__ float T0[256], T1[256], T2[256], CW[768];
  __shared__ float rs[256], rq[256];
  int tid = threadIdx.x;
  int b = blockIdx.y;
  size_t base_i = ((size_t)b * Nn + blockIdx.x * 16) * 16;
  T0[tid] = ts0[base_i + tid];
  T1[tid] = ts1[base_i + tid];
  T2[tid] = ts2[base_i + tid];
  for (int i = tid; i < 768; i += 256) CW[i] = cw[i];
  __syncthreads();
  int r = tid >> 4, o = tid & 15;
  float acc = 0.f;
#pragma unroll
  for (int f2 = 0; f2 < 16; ++f2) {
    acc += T0[r * 16 + f2] * CW[f2 * 16 + o];
    acc += T1[r * 16 + f2] * CW[256 + f2 * 16 + o];
    acc += T2[r * 16 + f2] * CW[512 + f2 * 16 + o];
  }
  float y = acc * 0.0625f + base[base_i + tid];
  ybuf[base_i + tid] = y;
  rs[tid] = y; rq[tid] = y * y;
  __syncthreads();
  for (int s2 = 128; s2 > 0; s2 >>= 1) {
    if (tid < s2) { rs[tid] += rs[tid + s2]; rq[tid] += rq[tid + s2]; }
    __syncthreads();
  }
  if (tid == 0) {
    atomicAdd(&lnacc[b * 2 + 0], rs[0]);
    atomicAdd(&lnacc[b * 2 + 1], rq[0]);
  }
}

// ---------------------------------------------------------------------------
// K_ln: layernorm over (N,O) per batch + relu
__global__ __launch_bounds__(256) void kln_k(
    const float* __restrict__ ybuf, const float* __restrict__ lnacc,
    const float* __restrict__ lg, const float* __restrict__ lb,
    float* __restrict__ outp) {
  int tid = threadIdx.x;
  int b = blockIdx.y;
  size_t i = ((size_t)b * Nn + blockIdx.x * 16) * 16 + tid;
  size_t nz = (size_t)blockIdx.x * 256 + tid;
  const float inv = 1.0f / 64000.0f;
  float s = lnacc[b * 2 + 0], q = lnacc[b * 2 + 1];
  float mean = s * inv;
  float var = q * inv - mean * mean;
  float rstd = rsqrtf(var + 1e-5f);
  float v = (ybuf[i] - mean) * rstd * lg[nz] + lb[nz];
  outp[i] = fmaxf(v, 0.f);
}

// ---------------------------------------------------------------------------
extern "C" void kernel_launch(void* const* d_in, const int* in_sizes, int n_in,
                              void* d_out, int out_size, void* d_ws, size_t ws_size,
                              hipStream_t stream) {
  const float* x   = (const float*)d_in[0];
  const float* lap = (const float*)d_in[1];
  const float* W1  = (const float*)d_in[2];
  const float* W2  = (const float*)d_in[3];
  const float* W3  = (const float*)d_in[4];
  const float* bs  = (const float*)d_in[5];
  const float* Vs  = (const float*)d_in[6];
  const float* U1  = (const float*)d_in[7];
  const float* U2  = (const float*)d_in[8];
  const float* U3  = (const float*)d_in[9];
  const float* be  = (const float*)d_in[10];
  const float* Ve  = (const float*)d_in[11];
  const float* cw  = (const float*)d_in[12];
  const float* tw  = (const float*)d_in[13];
  const float* tb  = (const float*)d_in[14];
  const float* lg  = (const float*)d_in[15];
  const float* lb  = (const float*)d_in[16];
  float* ws = (float*)d_ws;
  float* P    = ws;                    // per-batch, reused (NP floats)
  float* SP   = ws + (size_t)NP;       // per-batch, reused (NP floats)
  float* xts  = ws + (size_t)2 * NP;   // B*N*16
  float* slhs = xts + 256000;
  float* srhs = slhs + 256000;
  float* base = srhs + 256000;
  float* ts0  = base + 256000;
  float* ts1  = ts0 + 256000;
  float* ts2  = ts1 + 256000;
  float* ybuf = ts2 + 256000;
  float* tl   = ybuf + 256000;  // B*16
  float* tr   = tl + 64;        // B*16
  float* ecol = tr + 64;        // B*16
  float* rmx  = ecol + 64;      // N (per-batch reuse)
  float* rinv = rmx + 4000;     // N
  float* lnacc = rinv + 4000;   // B*2

  hipMemsetAsync(tl, 0, 128 * sizeof(float), stream);
  hipMemsetAsync(lnacc, 0, 8 * sizeof(float), stream);

  k1_trhs<<<dim3(16, 4), 256, 0, stream>>>(x, U1, U2, U3, tl, tr);
  k2_eattn<<<dim3(4), 256, 0, stream>>>(tl, tr, be, Ve, ecol);
  k3_pern<<<dim3(16, 4), 256, 0, stream>>>(x, ecol, W1, W2, W3, tw, tb,
                                           xts, slhs, srhs, base);
  for (int b = 0; b < 4; ++b) {
    gemm1_P<<<dim3(63, 63), 256, 0, stream>>>(slhs, srhs, bs, P, b);
    gemm2_spre<<<dim3(32, 32), 256, 0, stream>>>(Vs, P, SP);
    rowstat<<<dim3(4000), 256, 0, stream>>>(SP, rmx, rinv);
    txsum0_k<<<dim3(250), 256, 0, stream>>>(SP, xts, rmx, rinv, ts0, b);
  }
  cheb_k<<<dim3(250, 4), 256, 0, stream>>>(lap, ts0, nullptr, ts1, 1.0f);
  cheb_k<<<dim3(250, 4), 256, 0, stream>>>(lap, ts1, ts0, ts2, 2.0f);
  ky_k<<<dim3(250, 4), 256, 0, stream>>>(ts0, ts1, ts2, cw, base, ybuf, lnacc);
  kln_k<<<dim3(250, 4), 256, 0, stream>>>(ybuf, lnacc, lg, lb, (float*)d_out);
}

// Round 2
// 3180.150 us; speedup vs baseline: 2.2459x; 2.2459x over previous
//
#include <hip/hip_runtime.h>
#include <math.h>

#define Bc 4
#define Nn 4000
// padded N*N so float4 tile reads past col 3999 stay in-buffer
#define NP (16000000 + 4096)
#define BF_ELEMS 16384000  // 4096 rows x 4000 stride (bf16)

typedef short short8 __attribute__((ext_vector_type(8)));
typedef float f32x4 __attribute__((ext_vector_type(4)));
typedef unsigned short u16x4 __attribute__((ext_vector_type(4)));

static __device__ __forceinline__ unsigned short f2bf(float f) {
  unsigned u = __float_as_uint(f);
  unsigned r = (u + 0x7FFFu + ((u >> 16) & 1u)) >> 16;  // RNE
  return (unsigned short)r;
}
static __device__ __forceinline__ float bf2f(unsigned short h) {
  return __uint_as_float(((unsigned)h) << 16);
}
static __device__ __forceinline__ void gld16(const void* g, void* l) {
  __builtin_amdgcn_global_load_lds(
      (const __attribute__((address_space(1))) unsigned int*)g,
      (__attribute__((address_space(3))) unsigned int*)l, 16, 0, 0);
}

// ---------------------------------------------------------------------------
// K1: t_lhs[b,t] = sum_{n,f} x*U1[n] ; t_rhs[b,t] = sum_{n,f,g} x*U2[g,n]*U3[g]
__global__ __launch_bounds__(256) void k1_trhs(
    const float* __restrict__ x, const float* __restrict__ U1,
    const float* __restrict__ U2, const float* __restrict__ U3,
    float* __restrict__ tl, float* __restrict__ tr) {
  int b = blockIdx.y;
  int n = blockIdx.x * 256 + threadIdx.x;
  float xs[16];
#pragma unroll
  for (int t = 0; t < 16; ++t) xs[t] = 0.f;
  float c1 = 0.f, c2 = 0.f;
  if (n < Nn) {
    const float* xr = x + ((size_t)b * Nn + n) * 256;
    for (int f = 0; f < 16; ++f) {
#pragma unroll
      for (int q = 0; q < 4; ++q) {
        float4 v = *(const float4*)(xr + f * 16 + q * 4);
        xs[q * 4 + 0] += v.x; xs[q * 4 + 1] += v.y;
        xs[q * 4 + 2] += v.z; xs[q * 4 + 3] += v.w;
      }
    }
    c1 = U1[n];
#pragma unroll
    for (int g = 0; g < 16; ++g) c2 += U2[g * Nn + n] * U3[g];
  }
  int lane = threadIdx.x & 63;
#pragma unroll
  for (int t = 0; t < 16; ++t) {
    float v1 = c1 * xs[t];
    float v2 = c2 * xs[t];
#pragma unroll
    for (int off = 32; off > 0; off >>= 1) {
      v1 += __shfl_down(v1, off, 64);
      v2 += __shfl_down(v2, off, 64);
    }
    if (lane == 0) {
      atomicAdd(&tl[b * 16 + t], v1);
      atomicAdd(&tr[b * 16 + t], v2);
    }
  }
}

// ---------------------------------------------------------------------------
// K2: temporal attention, output Ecol[b,s] = sum_t E[b,t,s]
__global__ __launch_bounds__(256) void k2_eattn(
    const float* __restrict__ tl, const float* __restrict__ tr,
    const float* __restrict__ be, const float* __restrict__ Ve,
    float* __restrict__ ecol) {
  int b = blockIdx.x;
  int tid = threadIdx.x;
  __shared__ float sig[256];
  __shared__ float Em[256];
  int s = tid >> 4, r = tid & 15;
  float z = tl[b * 16 + s] * tr[b * 16 + r] + be[s * 16 + r];
  sig[s * 16 + r] = 1.0f / (1.0f + __expf(-z));
  __syncthreads();
  float e = 0.f;
#pragma unroll
  for (int ss = 0; ss < 16; ++ss) e += Ve[s * 16 + ss] * sig[ss * 16 + r];
  Em[s * 16 + r] = e;
  __syncthreads();
  if (tid < 16) {
    float m = -1e30f;
#pragma unroll
    for (int rr = 0; rr < 16; ++rr) m = fmaxf(m, Em[tid * 16 + rr]);
    float ssum = 0.f;
    float ex[16];
#pragma unroll
    for (int rr = 0; rr < 16; ++rr) { ex[rr] = __expf(Em[tid * 16 + rr] - m); ssum += ex[rr]; }
    float inv = 1.0f / ssum;
#pragma unroll
    for (int rr = 0; rr < 16; ++rr) Em[tid * 16 + rr] = ex[rr] * inv;
  }
  __syncthreads();
  if (tid < 16) {
    float c = 0.f;
#pragma unroll
    for (int tt = 0; tt < 16; ++tt) c += Em[tt * 16 + tid];
    ecol[b * 16 + tid] = c;
  }
}

// ---------------------------------------------------------------------------
// K3: per (b,n) contractions over x row
__global__ __launch_bounds__(256) void k3_pern(
    const float* __restrict__ x, const float* __restrict__ ecol,
    const float* __restrict__ W1, const float* __restrict__ W2,
    const float* __restrict__ W3, const float* __restrict__ time_w,
    const float* __restrict__ time_b,
    float* __restrict__ xts, float* __restrict__ slhs,
    float* __restrict__ srhs, float* __restrict__ base) {
  __shared__ float tws[4096];
  __shared__ float W1s[16], W3s[16], Ecs[16], tbs[16], W2s[256];
  int tid = threadIdx.x;
  int b = blockIdx.y;
  for (int i = tid; i < 4096; i += 256) tws[i] = time_w[i];
  W2s[tid] = W2[tid & 255];
  if (tid < 16) {
    W1s[tid] = W1[tid]; W3s[tid] = W3[tid];
    Ecs[tid] = ecol[b * 16 + tid]; tbs[tid] = time_b[tid];
  }
  __syncthreads();
  int n = blockIdx.x * 256 + tid;
  if (n >= Nn) return;
  const float* xr = x + ((size_t)b * Nn + n) * 256;
  float xtsv[16], slv[16], xw3[16], to[16], resid[16];
#pragma unroll
  for (int i = 0; i < 16; ++i) { xtsv[i] = 0; slv[i] = 0; xw3[i] = 0; to[i] = 0; }
  for (int f = 0; f < 16; ++f) {
    float xf[16];
#pragma unroll
    for (int q = 0; q < 4; ++q) {
      float4 v = *(const float4*)(xr + f * 16 + q * 4);
      xf[q * 4 + 0] = v.x; xf[q * 4 + 1] = v.y; xf[q * 4 + 2] = v.z; xf[q * 4 + 3] = v.w;
    }
    float a = 0, c = 0, d = 0;
#pragma unroll
    for (int t2 = 0; t2 < 16; ++t2) {
      a += Ecs[t2] * xf[t2];
      c += W1s[t2] * xf[t2];
      d += W3s[t2] * xf[t2];
    }
    xtsv[f] = a; slv[f] = c; xw3[f] = d; resid[f] = xf[15];
#pragma unroll
    for (int o = 0; o < 16; ++o) {
      float acc = 0;
#pragma unroll
      for (int t2 = 0; t2 < 16; ++t2) acc += tws[o * 256 + f * 16 + t2] * xf[t2];
      to[o] += acc;
    }
  }
  size_t o16 = ((size_t)b * Nn + n) * 16;
#pragma unroll
  for (int g = 0; g < 16; ++g) {
    float acc = 0;
#pragma unroll
    for (int k2 = 0; k2 < 16; ++k2) acc += W2s[g * 16 + k2] * xw3[k2];
    srhs[o16 + g] = acc;
  }
#pragma unroll
  for (int i = 0; i < 16; ++i) {
    xts[o16 + i] = xtsv[i];
    slhs[o16 + i] = slv[i];
    base[o16 + i] = to[i] + tbs[i] + resid[i];
  }
}

// ---------------------------------------------------------------------------
// vconv: Vs fp32 -> Vhi/Vlo bf16 (row stride 4000, rows >=4000 left as-is)
__global__ __launch_bounds__(256) void vconv(
    const float* __restrict__ Vs, unsigned short* __restrict__ Vhi,
    unsigned short* __restrict__ Vlo) {
  size_t i = ((size_t)blockIdx.x * 256 + threadIdx.x) * 4;
  float4 v = *(const float4*)(Vs + i);
  u16x4 h, l;
  h.x = f2bf(v.x); l.x = f2bf(v.x - bf2f(h.x));
  h.y = f2bf(v.y); l.y = f2bf(v.y - bf2f(h.y));
  h.z = f2bf(v.z); l.z = f2bf(v.z - bf2f(h.z));
  h.w = f2bf(v.w); l.w = f2bf(v.w - bf2f(h.w));
  *(u16x4*)(Vhi + i) = h;
  *(u16x4*)(Vlo + i) = l;
}

// ---------------------------------------------------------------------------
// GEMM1: BT[c][n] = sigmoid(srhs[b,c]·slhs[b,n] + bs[n,c]) as bf16 hi/lo
// (BT is B^T for gemm2: row c = output col of SP, col n = contraction dim)
__global__ __launch_bounds__(256) void gemm1_P(
    const float* __restrict__ slhs, const float* __restrict__ srhs,
    const float* __restrict__ bsm, unsigned short* __restrict__ PhiT,
    unsigned short* __restrict__ PloT, int b) {
  __shared__ float Cs[64][17];
  __shared__ float Ms[64][17];
  int tid = threadIdx.x;
  int c0 = blockIdx.y * 64, n0 = blockIdx.x * 64;
  int lr = tid >> 2, lq = (tid & 3) << 2;
  {
    int gc = c0 + lr; if (gc > Nn - 1) gc = Nn - 1;
    float4 v = *(const float4*)(srhs + ((size_t)b * Nn + gc) * 16 + lq);
    Cs[lr][lq + 0] = v.x; Cs[lr][lq + 1] = v.y; Cs[lr][lq + 2] = v.z; Cs[lr][lq + 3] = v.w;
    int gn = n0 + lr; if (gn > Nn - 1) gn = Nn - 1;
    float4 w = *(const float4*)(slhs + ((size_t)b * Nn + gn) * 16 + lq);
    Ms[lr][lq + 0] = w.x; Ms[lr][lq + 1] = w.y; Ms[lr][lq + 2] = w.z; Ms[lr][lq + 3] = w.w;
  }
  __syncthreads();
  int tx = tid & 15, ty = tid >> 4;  // ty -> c rows, tx -> n cols
  float acc[4][4] = {};
#pragma unroll
  for (int f = 0; f < 16; ++f) {
    float a4[4], b4[4];
#pragma unroll
    for (int i = 0; i < 4; ++i) a4[i] = Cs[ty * 4 + i][f];
#pragma unroll
    for (int j = 0; j < 4; ++j) b4[j] = Ms[tx * 4 + j][f];
#pragma unroll
    for (int i = 0; i < 4; ++i)
#pragma unroll
      for (int j = 0; j < 4; ++j) acc[i][j] += a4[i] * b4[j];
  }
#pragma unroll
  for (int i = 0; i < 4; ++i) {
    int c = c0 + ty * 4 + i;
#pragma unroll
    for (int j = 0; j < 4; ++j) {
      int n = n0 + tx * 4 + j;
      if (n < Nn) {
        float z = acc[i][j];
        if (c < Nn) z += bsm[(size_t)n * Nn + c];
        float p = 1.f / (1.f + __expf(-z));
        unsigned short hi = f2bf(p);
        PhiT[(size_t)c * Nn + n] = hi;
        PloT[(size_t)c * Nn + n] = f2bf(p - bf2f(hi));
      }
    }
  }
}

// ---------------------------------------------------------------------------
// GEMM2 via split-bf16 MFMA: SP[r][c] = sum_n Vs[r][n]*P[n][c]
//   = Vhi@Bh + Vhi@Bl + Vlo@Bh  (lo*lo dropped)
// 128x128 tile, BK=32, 4 waves x 64x64, mfma_f32_16x16x32_bf16.
__global__ __launch_bounds__(256) void gemm2_mfma(
    const unsigned short* __restrict__ Vhi, const unsigned short* __restrict__ Vlo,
    const unsigned short* __restrict__ PhiT, const unsigned short* __restrict__ PloT,
    float* __restrict__ SP) {
  __shared__ unsigned short Ah[128 * 32];
  __shared__ unsigned short Al[128 * 32];
  __shared__ unsigned short Bh[128 * 32];
  __shared__ unsigned short Bl[128 * 32];
  int t = threadIdx.x;
  // XCD-aware rasterization: pm = pid%8 + 8*(pid/256), pn = (pid/8)%32
  int pid = blockIdx.x;
  int pm = (pid & 7) | ((pid >> 8) << 3);
  int pn = (pid >> 3) & 31;
  int row0 = pm * 128, col0 = pn * 128;

  // staging addresses: lane t covers LDS shorts [t*8, t*8+8), row t>>2, k-oct t&3
  size_t a_base = (size_t)(row0 + (t >> 2)) * Nn + (t & 3) * 8;
  size_t b_base = (size_t)(col0 + (t >> 2)) * Nn + (t & 3) * 8;

  int lane = t & 63;
  int wid = t >> 6;
  int wm = (wid >> 1) * 64, wn = (wid & 1) * 64;
  int ml = lane & 15, qd = lane >> 4;
  int aoff = (wm + ml) * 32 + qd * 8;
  int boff = (wn + ml) * 32 + qd * 8;

  f32x4 acc[4][4] = {};

  for (int k0 = 0; k0 < Nn; k0 += 32) {
    gld16(Vhi + a_base + k0, &Ah[t * 8]);
    gld16(Vhi + a_base + (size_t)64 * Nn + k0, &Ah[2048 + t * 8]);
    gld16(Vlo + a_base + k0, &Al[t * 8]);
    gld16(Vlo + a_base + (size_t)64 * Nn + k0, &Al[2048 + t * 8]);
    gld16(PhiT + b_base + k0, &Bh[t * 8]);
    gld16(PhiT + b_base + (size_t)64 * Nn + k0, &Bh[2048 + t * 8]);
    gld16(PloT + b_base + k0, &Bl[t * 8]);
    gld16(PloT + b_base + (size_t)64 * Nn + k0, &Bl[2048 + t * 8]);
    __syncthreads();
    short8 a_h[4], a_l[4], b_h[4], b_l[4];
#pragma unroll
    for (int i = 0; i < 4; ++i) {
      a_h[i] = *(const short8*)&Ah[aoff + i * 512];
      a_l[i] = *(const short8*)&Al[aoff + i * 512];
    }
#pragma unroll
    for (int j = 0; j < 4; ++j) {
      b_h[j] = *(const short8*)&Bh[boff + j * 512];
      b_l[j] = *(const short8*)&Bl[boff + j * 512];
    }
#pragma unroll
    for (int i = 0; i < 4; ++i)
#pragma unroll
      for (int j = 0; j < 4; ++j) {
        acc[i][j] = __builtin_amdgcn_mfma_f32_16x16x32_bf16(a_h[i], b_h[j], acc[i][j], 0, 0, 0);
        acc[i][j] = __builtin_amdgcn_mfma_f32_16x16x32_bf16(a_h[i], b_l[j], acc[i][j], 0, 0, 0);
        acc[i][j] = __builtin_amdgcn_mfma_f32_16x16x32_bf16(a_l[i], b_h[j], acc[i][j], 0, 0, 0);
      }
    __syncthreads();
  }
  // C/D layout: col = lane&15, row = (lane>>4)*4 + reg  [m89-verified]
#pragma unroll
  for (int i = 0; i < 4; ++i)
#pragma unroll
    for (int j = 0; j < 4; ++j) {
      int gcol = col0 + wn + j * 16 + ml;
#pragma unroll
      for (int r = 0; r < 4; ++r) {
        int grow = row0 + wm + i * 16 + qd * 4 + r;
        if (grow < Nn && gcol < Nn)
          SP[(size_t)grow * Nn + gcol] = acc[i][j][r];
      }
    }
}

// ---------------------------------------------------------------------------
// rowstat: per-row max and 1/sum(exp) over SP row
__global__ __launch_bounds__(256) void rowstat(
    const float* __restrict__ SP, float* __restrict__ rmx, float* __restrict__ rinv) {
  int n = blockIdx.x;
  int tid = threadIdx.x;
  const float* row = SP + (size_t)n * Nn;
  __shared__ float red[256];
  float m = -3.0e38f;
  for (int k = tid; k < Nn; k += 256) m = fmaxf(m, row[k]);
  red[tid] = m;
  __syncthreads();
  for (int s2 = 128; s2 > 0; s2 >>= 1) {
    if (tid < s2) red[tid] = fmaxf(red[tid], red[tid + s2]);
    __syncthreads();
  }
  float rm = red[0];
  __syncthreads();
  float ssum = 0.f;
  for (int k = tid; k < Nn; k += 256) ssum += __expf(row[k] - rm);
  red[tid] = ssum;
  __syncthreads();
  for (int s2 = 128; s2 > 0; s2 >>= 1) {
    if (tid < s2) red[tid] += red[tid + s2];
    __syncthreads();
  }
  if (tid == 0) { rmx[n] = rm; rinv[n] = 1.0f / red[0]; }
}

// ---------------------------------------------------------------------------
// txsum0: ts0[b,n,f] = sum_k softmax(SP)[n,k] * xts[b,k,f]
__global__ __launch_bounds__(256) void txsum0_k(
    const float* __restrict__ SP, const float* __restrict__ xts,
    const float* __restrict__ rmx, const float* __restrict__ rinv,
    float* __restrict__ ts0, int b) {
  __shared__ float Ws[16][65];
  __shared__ float Xs[64][17];
  int tid = threadIdx.x;
  int n0 = blockIdx.x * 16;
  int r = tid >> 4, f = tid & 15;
  int xr = tid >> 2, xc = (tid & 3) << 2;
  float rm = rmx[n0 + r], ri = rinv[n0 + r];
  float acc = 0.f;
  for (int k0 = 0; k0 < Nn; k0 += 64) {
    int gk4 = k0 + f * 4;
    {
      float4 v = *(const float4*)(SP + (size_t)(n0 + r) * Nn + gk4);  // pad-safe
      Ws[r][f * 4 + 0] = (gk4 + 0 < Nn) ? __expf(v.x - rm) * ri : 0.f;
      Ws[r][f * 4 + 1] = (gk4 + 1 < Nn) ? __expf(v.y - rm) * ri : 0.f;
      Ws[r][f * 4 + 2] = (gk4 + 2 < Nn) ? __expf(v.z - rm) * ri : 0.f;
      Ws[r][f * 4 + 3] = (gk4 + 3 < Nn) ? __expf(v.w - rm) * ri : 0.f;
    }
    int gk = k0 + xr;
    if (gk < Nn) {
      float4 v = *(const float4*)(xts + ((size_t)b * Nn + gk) * 16 + xc);
      Xs[xr][xc + 0] = v.x; Xs[xr][xc + 1] = v.y; Xs[xr][xc + 2] = v.z; Xs[xr][xc + 3] = v.w;
    } else {
      Xs[xr][xc + 0] = 0.f; Xs[xr][xc + 1] = 0.f; Xs[xr][xc + 2] = 0.f; Xs[xr][xc + 3] = 0.f;
    }
    __syncthreads();
#pragma unroll
    for (int kk = 0; kk < 64; ++kk) acc += Ws[r][kk] * Xs[kk][f];
    __syncthreads();
  }
  ts0[((size_t)b * Nn + n0 + r) * 16 + f] = acc;
}

// ---------------------------------------------------------------------------
// cheb: Cout[b,n,f] = scale * sum_m A[n,m]*Bin[b,m,f] - (C0 ? C0 : 0)
__global__ __launch_bounds__(256) void cheb_k(
    const float* __restrict__ A, const float* __restrict__ Bin,
    const float* __restrict__ C0, float* __restrict__ Cout, float scale) {
  __shared__ float Ws[16][65];
  __shared__ float Xs[64][17];
  int tid = threadIdx.x;
  int b = blockIdx.y;
  int n0 = blockIdx.x * 16;
  int r = tid >> 4, f = tid & 15;
  int xr = tid >> 2, xc = (tid & 3) << 2;
  float acc = 0.f;
  for (int k0 = 0; k0 < Nn; k0 += 64) {
    int gk4 = k0 + f * 4;
    if (gk4 + 3 < Nn) {
      float4 v = *(const float4*)(A + (size_t)(n0 + r) * Nn + gk4);
      Ws[r][f * 4 + 0] = v.x; Ws[r][f * 4 + 1] = v.y;
      Ws[r][f * 4 + 2] = v.z; Ws[r][f * 4 + 3] = v.w;
    } else {
      for (int q = 0; q < 4; ++q)
        Ws[r][f * 4 + q] = (gk4 + q < Nn) ? A[(size_t)(n0 + r) * Nn + gk4 + q] : 0.f;
    }
    int gk = k0 + xr;
    if (gk < Nn) {
      float4 v = *(const float4*)(Bin + ((size_t)b * Nn + gk) * 16 + xc);
      Xs[xr][xc + 0] = v.x; Xs[xr][xc + 1] = v.y; Xs[xr][xc + 2] = v.z; Xs[xr][xc + 3] = v.w;
    } else {
      Xs[xr][xc + 0] = 0.f; Xs[xr][xc + 1] = 0.f; Xs[xr][xc + 2] = 0.f; Xs[xr][xc + 3] = 0.f;
    }
    __syncthreads();
#pragma unroll
    for (int kk = 0; kk < 64; ++kk) acc += Ws[r][kk] * Xs[kk][f];
    __syncthreads();
  }
  size_t idx = ((size_t)b * Nn + n0 + r) * 16 + f;
  float v = scale * acc;
  if (C0) v -= C0[idx];
  Cout[idx] = v;
}

// ---------------------------------------------------------------------------
// K_y: y = (1/16)*sum_k sum_f tsk[n,f]*cw[k,f,o] + base ; accumulate LN stats
__global__ __launch_bounds__(256) void ky_k(
    const float* __restrict__ ts0, const float* __restrict__ ts1,
    const float* __restrict__ ts2, const float* __restrict__ cw,
    const float* __restrict__ base, float* __restrict__ ybuf,
    float* __restrict__ lnacc) {
  __shared__ float T0[256], T1[256], T2[256], CW[768];
  __shared__ float rs[256], rq[256];
  int tid = threadIdx.x;
  int b = blockIdx.y;
  size_t base_i = ((size_t)b * Nn + blockIdx.x * 16) * 16;
  T0[tid] = ts0[base_i + tid];
  T1[tid] = ts1[base_i + tid];
  T2[tid] = ts2[base_i + tid];
  for (int i = tid; i < 768; i += 256) CW[i] = cw[i];
  __syncthreads();
  int r = tid >> 4, o = tid & 15;
  float acc = 0.f;
#pragma unroll
  for (int f2 = 0; f2 < 16; ++f2) {
    acc += T0[r * 16 + f2] * CW[f2 * 16 + o];
    acc += T1[r * 16 + f2] * CW[256 + f2 * 16 + o];
    acc += T2[r * 16 + f2] * CW[512 + f2 * 16 + o];
  }
  float y = acc * 0.0625f + base[base_i + tid];
  ybuf[base_i + tid] = y;
  rs[tid] = y; rq[tid] = y * y;
  __syncthreads();
  for (int s2 = 128; s2 > 0; s2 >>= 1) {
    if (tid < s2) { rs[tid] += rs[tid + s2]; rq[tid] += rq[tid + s2]; }
    __syncthreads();
  }
  if (tid == 0) {
    atomicAdd(&lnacc[b * 2 + 0], rs[0]);
    atomicAdd(&lnacc[b * 2 + 1], rq[0]);
  }
}

// ---------------------------------------------------------------------------
// K_ln: layernorm over (N,O) per batch + relu
__global__ __launch_bounds__(256) void kln_k(
    const float* __restrict__ ybuf, const float* __restrict__ lnacc,
    const float* __restrict__ lg, const float* __restrict__ lb,
    float* __restrict__ outp) {
  int tid = threadIdx.x;
  int b = blockIdx.y;
  size_t i = ((size_t)b * Nn + blockIdx.x * 16) * 16 + tid;
  size_t nz = (size_t)blockIdx.x * 256 + tid;
  const float inv = 1.0f / 64000.0f;
  float s = lnacc[b * 2 + 0], q = lnacc[b * 2 + 1];
  float mean = s * inv;
  float var = q * inv - mean * mean;
  float rstd = rsqrtf(var + 1e-5f);
  float v = (ybuf[i] - mean) * rstd * lg[nz] + lb[nz];
  outp[i] = fmaxf(v, 0.f);
}

// ---------------------------------------------------------------------------
extern "C" void kernel_launch(void* const* d_in, const int* in_sizes, int n_in,
                              void* d_out, int out_size, void* d_ws, size_t ws_size,
                              hipStream_t stream) {
  const float* x   = (const float*)d_in[0];
  const float* lap = (const float*)d_in[1];
  const float* W1  = (const float*)d_in[2];
  const float* W2  = (const float*)d_in[3];
  const float* W3  = (const float*)d_in[4];
  const float* bs  = (const float*)d_in[5];
  const float* Vs  = (const float*)d_in[6];
  const float* U1  = (const float*)d_in[7];
  const float* U2  = (const float*)d_in[8];
  const float* U3  = (const float*)d_in[9];
  const float* be  = (const float*)d_in[10];
  const float* Ve  = (const float*)d_in[11];
  const float* cw  = (const float*)d_in[12];
  const float* tw  = (const float*)d_in[13];
  const float* tb  = (const float*)d_in[14];
  const float* lg  = (const float*)d_in[15];
  const float* lb  = (const float*)d_in[16];
  float* ws = (float*)d_ws;
  float* SP = ws;  // NP floats
  unsigned short* Vhi  = (unsigned short*)(ws + (size_t)NP);
  unsigned short* Vlo  = Vhi + (size_t)BF_ELEMS;
  unsigned short* PhiT = Vlo + (size_t)BF_ELEMS;
  unsigned short* PloT = PhiT + (size_t)BF_ELEMS;
  float* xts  = (float*)(PloT + (size_t)BF_ELEMS);
  float* slhs = xts + 256000;
  float* srhs = slhs + 256000;
  float* base = srhs + 256000;
  float* ts0  = base + 256000;
  float* ts1  = ts0 + 256000;
  float* ts2  = ts1 + 256000;
  float* ybuf = ts2 + 256000;
  float* tl   = ybuf + 256000;  // B*16
  float* tr   = tl + 64;
  float* ecol = tr + 64;
  float* rmx  = ecol + 64;  // N
  float* rinv = rmx + 4000;
  float* lnacc = rinv + 4000;  // B*2

  hipMemsetAsync(tl, 0, 128 * sizeof(float), stream);
  hipMemsetAsync(lnacc, 0, 8 * sizeof(float), stream);

  k1_trhs<<<dim3(16, 4), 256, 0, stream>>>(x, U1, U2, U3, tl, tr);
  k2_eattn<<<dim3(4), 256, 0, stream>>>(tl, tr, be, Ve, ecol);
  k3_pern<<<dim3(16, 4), 256, 0, stream>>>(x, ecol, W1, W2, W3, tw, tb,
                                           xts, slhs, srhs, base);
  vconv<<<dim3(15625), 256, 0, stream>>>(Vs, Vhi, Vlo);
  for (int b = 0; b < 4; ++b) {
    gemm1_P<<<dim3(63, 63), 256, 0, stream>>>(slhs, srhs, bs, PhiT, PloT, b);
    gemm2_mfma<<<dim3(1024), 256, 0, stream>>>(Vhi, Vlo, PhiT, PloT, SP);
    rowstat<<<dim3(4000), 256, 0, stream>>>(SP, rmx, rinv);
    txsum0_k<<<dim3(250), 256, 0, stream>>>(SP, xts, rmx, rinv, ts0, b);
  }
  cheb_k<<<dim3(250, 4), 256, 0, stream>>>(lap, ts0, nullptr, ts1, 1.0f);
  cheb_k<<<dim3(250, 4), 256, 0, stream>>>(lap, ts1, ts0, ts2, 2.0f);
  ky_k<<<dim3(250, 4), 256, 0, stream>>>(ts0, ts1, ts2, cw, base, ybuf, lnacc);
  kln_k<<<dim3(250, 4), 256, 0, stream>>>(ybuf, lnacc, lg, lb, (float*)d_out);
}

// Round 3
// 2593.434 us; speedup vs baseline: 2.7540x; 1.2262x over previous
//
#include <hip/hip_runtime.h>
#include <math.h>

#define Bc 4
#define Nn 4000
#define NP (16000000 + 4096)
#define BF_ELEMS 16384000  // 4096 rows x 4000 stride (16-bit elems)

typedef _Float16 half8 __attribute__((ext_vector_type(8)));
typedef float f32x4 __attribute__((ext_vector_type(4)));
typedef unsigned short u16x4 __attribute__((ext_vector_type(4)));

static __device__ __forceinline__ unsigned short f2h(float f) {
  _Float16 h = (_Float16)f;
  unsigned short u;
  __builtin_memcpy(&u, &h, 2);
  return u;
}
static __device__ __forceinline__ float h2f(unsigned short u) {
  _Float16 h;
  __builtin_memcpy(&h, &u, 2);
  return (float)h;
}
static __device__ __forceinline__ void gld16(const void* g, void* l) {
  __builtin_amdgcn_global_load_lds(
      (const __attribute__((address_space(1))) unsigned int*)g,
      (__attribute__((address_space(3))) unsigned int*)l, 16, 0, 0);
}

// ---------------------------------------------------------------------------
// K1: t_lhs[b,t] = sum_{n,f} x*U1[n] ; t_rhs[b,t] = sum_{n,f,g} x*U2[g,n]*U3[g]
__global__ __launch_bounds__(256) void k1_trhs(
    const float* __restrict__ x, const float* __restrict__ U1,
    const float* __restrict__ U2, const float* __restrict__ U3,
    float* __restrict__ tl, float* __restrict__ tr) {
  int b = blockIdx.y;
  int n = blockIdx.x * 256 + threadIdx.x;
  float xs[16];
#pragma unroll
  for (int t = 0; t < 16; ++t) xs[t] = 0.f;
  float c1 = 0.f, c2 = 0.f;
  if (n < Nn) {
    const float* xr = x + ((size_t)b * Nn + n) * 256;
    for (int f = 0; f < 16; ++f) {
#pragma unroll
      for (int q = 0; q < 4; ++q) {
        float4 v = *(const float4*)(xr + f * 16 + q * 4);
        xs[q * 4 + 0] += v.x; xs[q * 4 + 1] += v.y;
        xs[q * 4 + 2] += v.z; xs[q * 4 + 3] += v.w;
      }
    }
    c1 = U1[n];
#pragma unroll
    for (int g = 0; g < 16; ++g) c2 += U2[g * Nn + n] * U3[g];
  }
  int lane = threadIdx.x & 63;
#pragma unroll
  for (int t = 0; t < 16; ++t) {
    float v1 = c1 * xs[t];
    float v2 = c2 * xs[t];
#pragma unroll
    for (int off = 32; off > 0; off >>= 1) {
      v1 += __shfl_down(v1, off, 64);
      v2 += __shfl_down(v2, off, 64);
    }
    if (lane == 0) {
      atomicAdd(&tl[b * 16 + t], v1);
      atomicAdd(&tr[b * 16 + t], v2);
    }
  }
}

// ---------------------------------------------------------------------------
// K2: temporal attention, output Ecol[b,s] = sum_t E[b,t,s]
__global__ __launch_bounds__(256) void k2_eattn(
    const float* __restrict__ tl, const float* __restrict__ tr,
    const float* __restrict__ be, const float* __restrict__ Ve,
    float* __restrict__ ecol) {
  int b = blockIdx.x;
  int tid = threadIdx.x;
  __shared__ float sig[256];
  __shared__ float Em[256];
  int s = tid >> 4, r = tid & 15;
  float z = tl[b * 16 + s] * tr[b * 16 + r] + be[s * 16 + r];
  sig[s * 16 + r] = 1.0f / (1.0f + __expf(-z));
  __syncthreads();
  float e = 0.f;
#pragma unroll
  for (int ss = 0; ss < 16; ++ss) e += Ve[s * 16 + ss] * sig[ss * 16 + r];
  Em[s * 16 + r] = e;
  __syncthreads();
  if (tid < 16) {
    float m = -1e30f;
#pragma unroll
    for (int rr = 0; rr < 16; ++rr) m = fmaxf(m, Em[tid * 16 + rr]);
    float ssum = 0.f;
    float ex[16];
#pragma unroll
    for (int rr = 0; rr < 16; ++rr) { ex[rr] = __expf(Em[tid * 16 + rr] - m); ssum += ex[rr]; }
    float inv = 1.0f / ssum;
#pragma unroll
    for (int rr = 0; rr < 16; ++rr) Em[tid * 16 + rr] = ex[rr] * inv;
  }
  __syncthreads();
  if (tid < 16) {
    float c = 0.f;
#pragma unroll
    for (int tt = 0; tt < 16; ++tt) c += Em[tt * 16 + tid];
    ecol[b * 16 + tid] = c;
  }
}

// ---------------------------------------------------------------------------
// K3: per (b,n) contractions over x row
__global__ __launch_bounds__(256) void k3_pern(
    const float* __restrict__ x, const float* __restrict__ ecol,
    const float* __restrict__ W1, const float* __restrict__ W2,
    const float* __restrict__ W3, const float* __restrict__ time_w,
    const float* __restrict__ time_b,
    float* __restrict__ xts, float* __restrict__ slhs,
    float* __restrict__ srhs, float* __restrict__ base) {
  __shared__ float tws[4096];
  __shared__ float W1s[16], W3s[16], Ecs[16], tbs[16], W2s[256];
  int tid = threadIdx.x;
  int b = blockIdx.y;
  for (int i = tid; i < 4096; i += 256) tws[i] = time_w[i];
  W2s[tid] = W2[tid & 255];
  if (tid < 16) {
    W1s[tid] = W1[tid]; W3s[tid] = W3[tid];
    Ecs[tid] = ecol[b * 16 + tid]; tbs[tid] = time_b[tid];
  }
  __syncthreads();
  int n = blockIdx.x * 256 + tid;
  if (n >= Nn) return;
  const float* xr = x + ((size_t)b * Nn + n) * 256;
  float xtsv[16], slv[16], xw3[16], to[16], resid[16];
#pragma unroll
  for (int i = 0; i < 16; ++i) { xtsv[i] = 0; slv[i] = 0; xw3[i] = 0; to[i] = 0; }
  for (int f = 0; f < 16; ++f) {
    float xf[16];
#pragma unroll
    for (int q = 0; q < 4; ++q) {
      float4 v = *(const float4*)(xr + f * 16 + q * 4);
      xf[q * 4 + 0] = v.x; xf[q * 4 + 1] = v.y; xf[q * 4 + 2] = v.z; xf[q * 4 + 3] = v.w;
    }
    float a = 0, c = 0, d = 0;
#pragma unroll
    for (int t2 = 0; t2 < 16; ++t2) {
      a += Ecs[t2] * xf[t2];
      c += W1s[t2] * xf[t2];
      d += W3s[t2] * xf[t2];
    }
    xtsv[f] = a; slv[f] = c; xw3[f] = d; resid[f] = xf[15];
#pragma unroll
    for (int o = 0; o < 16; ++o) {
      float acc = 0;
#pragma unroll
      for (int t2 = 0; t2 < 16; ++t2) acc += tws[o * 256 + f * 16 + t2] * xf[t2];
      to[o] += acc;
    }
  }
  size_t o16 = ((size_t)b * Nn + n) * 16;
#pragma unroll
  for (int g = 0; g < 16; ++g) {
    float acc = 0;
#pragma unroll
    for (int k2 = 0; k2 < 16; ++k2) acc += W2s[g * 16 + k2] * xw3[k2];
    srhs[o16 + g] = acc;
  }
#pragma unroll
  for (int i = 0; i < 16; ++i) {
    xts[o16 + i] = xtsv[i];
    slhs[o16 + i] = slv[i];
    base[o16 + i] = to[i] + tbs[i] + resid[i];
  }
}

// ---------------------------------------------------------------------------
// vconv: Vs fp32 -> Vhi/Vlo fp16 split (values in (0,1), fp16-safe)
__global__ __launch_bounds__(256) void vconv(
    const float* __restrict__ Vs, unsigned short* __restrict__ Vhi,
    unsigned short* __restrict__ Vlo) {
  size_t i = ((size_t)blockIdx.x * 256 + threadIdx.x) * 4;
  float4 v = *(const float4*)(Vs + i);
  u16x4 h, l;
  h.x = f2h(v.x); l.x = f2h(v.x - h2f(h.x));
  h.y = f2h(v.y); l.y = f2h(v.y - h2f(h.y));
  h.z = f2h(v.z); l.z = f2h(v.z - h2f(h.z));
  h.w = f2h(v.w); l.w = f2h(v.w - h2f(h.w));
  *(u16x4*)(Vhi + i) = h;
  *(u16x4*)(Vlo + i) = l;
}

// ---------------------------------------------------------------------------
// GEMM1: P[m,k] = sigmoid(slhs[b,m]·srhs[b,k] + bs[m,k]); store P^T (fp16)
// bs read row-contiguous (float4); output transposed through LDS.
__global__ __launch_bounds__(256) void gemm1_P(
    const float* __restrict__ slhs, const float* __restrict__ srhs,
    const float* __restrict__ bsm, unsigned short* __restrict__ PhT, int b) {
  __shared__ float Ms[64][17];     // slhs rows (m)
  __shared__ float Cs[64][17];     // srhs rows (k)
  __shared__ float Pt[64][65];     // P[m][k] tile
  int tid = threadIdx.x;
  int m0 = blockIdx.y * 64, k0 = blockIdx.x * 64;
  int lr = tid >> 2, lq = (tid & 3) << 2;
  {
    int gm = m0 + lr; if (gm > Nn - 1) gm = Nn - 1;
    float4 v = *(const float4*)(slhs + ((size_t)b * Nn + gm) * 16 + lq);
    Ms[lr][lq + 0] = v.x; Ms[lr][lq + 1] = v.y; Ms[lr][lq + 2] = v.z; Ms[lr][lq + 3] = v.w;
    int gk = k0 + lr; if (gk > Nn - 1) gk = Nn - 1;
    float4 w = *(const float4*)(srhs + ((size_t)b * Nn + gk) * 16 + lq);
    Cs[lr][lq + 0] = w.x; Cs[lr][lq + 1] = w.y; Cs[lr][lq + 2] = w.z; Cs[lr][lq + 3] = w.w;
  }
  __syncthreads();
  int tx = tid & 15, ty = tid >> 4;  // ty -> m rows (i), tx -> k cols (j)
  float acc[4][4] = {};
#pragma unroll
  for (int f = 0; f < 16; ++f) {
    float a4[4], b4[4];
#pragma unroll
    for (int i = 0; i < 4; ++i) a4[i] = Ms[ty * 4 + i][f];
#pragma unroll
    for (int j = 0; j < 4; ++j) b4[j] = Cs[tx * 4 + j][f];
#pragma unroll
    for (int i = 0; i < 4; ++i)
#pragma unroll
      for (int j = 0; j < 4; ++j) acc[i][j] += a4[i] * b4[j];
  }
#pragma unroll
  for (int i = 0; i < 4; ++i) {
    int m = m0 + ty * 4 + i;
    int k = k0 + tx * 4;
    float bv[4] = {0.f, 0.f, 0.f, 0.f};
    if (m < Nn) {
      if (k + 3 < Nn) {
        float4 t = *(const float4*)(bsm + (size_t)m * Nn + k);
        bv[0] = t.x; bv[1] = t.y; bv[2] = t.z; bv[3] = t.w;
      } else {
        for (int j = 0; j < 4; ++j)
          if (k + j < Nn) bv[j] = bsm[(size_t)m * Nn + k + j];
      }
    }
#pragma unroll
    for (int j = 0; j < 4; ++j) {
      float z = acc[i][j] + bv[j];
      Pt[ty * 4 + i][tx * 4 + j] = 1.f / (1.f + __expf(-z));
    }
  }
  __syncthreads();
  // transposed store: PhT[k][m], hi fp16 only (lo of P dropped — 2-term split)
#pragma unroll
  for (int i = 0; i < 4; ++i) {
    int kl = ty * 4 + i;
    int ml = tx * 4;
    int gm = m0 + ml;
    u16x4 h;
    h.x = f2h(Pt[ml + 0][kl]);
    h.y = f2h(Pt[ml + 1][kl]);
    h.z = f2h(Pt[ml + 2][kl]);
    h.w = f2h(Pt[ml + 3][kl]);
    size_t off = (size_t)(k0 + kl) * Nn + gm;
    if (gm + 3 < Nn) {
      *(u16x4*)(PhT + off) = h;
    } else {
      unsigned short hv[4] = {h.x, h.y, h.z, h.w};
      for (int q = 0; q < 4; ++q)
        if (gm + q < Nn) PhT[off + q] = hv[q];
    }
  }
}

// ---------------------------------------------------------------------------
// GEMM2 via 2-term fp16 split MFMA: SP[r][c] = sum_n V[r][n]*P[n][c]
//   ≈ Vh@Ph + Vl@Ph   (V@Pl dropped: RMS logit err ~4e-3)
// 128x128 tile, BK=32, 4 waves x 64x64, mfma_f32_16x16x32_f16.
__global__ __launch_bounds__(256) void gemm2_mfma(
    const unsigned short* __restrict__ Vhi, const unsigned short* __restrict__ Vlo,
    const unsigned short* __restrict__ PhT, float* __restrict__ SP) {
  __shared__ unsigned short Ah[128 * 32];
  __shared__ unsigned short Al[128 * 32];
  __shared__ unsigned short Bh[128 * 32];
  int t = threadIdx.x;
  int pid = blockIdx.x;
  int pm = (pid & 7) | ((pid >> 8) << 3);
  int pn = (pid >> 3) & 31;
  int row0 = pm * 128, col0 = pn * 128;

  size_t a_base = (size_t)(row0 + (t >> 2)) * Nn + (t & 3) * 8;
  size_t b_base = (size_t)(col0 + (t >> 2)) * Nn + (t & 3) * 8;

  int lane = t & 63;
  int wid = t >> 6;
  int wm = (wid >> 1) * 64, wn = (wid & 1) * 64;
  int ml = lane & 15, qd = lane >> 4;
  int aoff = (wm + ml) * 32 + qd * 8;
  int boff = (wn + ml) * 32 + qd * 8;

  f32x4 acc[4][4] = {};

  for (int k0 = 0; k0 < Nn; k0 += 32) {
    gld16(Vhi + a_base + k0, &Ah[t * 8]);
    gld16(Vhi + a_base + (size_t)64 * Nn + k0, &Ah[2048 + t * 8]);
    gld16(Vlo + a_base + k0, &Al[t * 8]);
    gld16(Vlo + a_base + (size_t)64 * Nn + k0, &Al[2048 + t * 8]);
    gld16(PhT + b_base + k0, &Bh[t * 8]);
    gld16(PhT + b_base + (size_t)64 * Nn + k0, &Bh[2048 + t * 8]);
    __syncthreads();
    half8 a_h[4], a_l[4], b_h[4];
#pragma unroll
    for (int i = 0; i < 4; ++i) {
      a_h[i] = *(const half8*)&Ah[aoff + i * 512];
      a_l[i] = *(const half8*)&Al[aoff + i * 512];
    }
#pragma unroll
    for (int j = 0; j < 4; ++j) b_h[j] = *(const half8*)&Bh[boff + j * 512];
#pragma unroll
    for (int i = 0; i < 4; ++i)
#pragma unroll
      for (int j = 0; j < 4; ++j) {
        acc[i][j] = __builtin_amdgcn_mfma_f32_16x16x32_f16(a_h[i], b_h[j], acc[i][j], 0, 0, 0);
        acc[i][j] = __builtin_amdgcn_mfma_f32_16x16x32_f16(a_l[i], b_h[j], acc[i][j], 0, 0, 0);
      }
    __syncthreads();
  }
  // C/D layout: col = lane&15, row = (lane>>4)*4 + reg  [m89-verified]
#pragma unroll
  for (int i = 0; i < 4; ++i)
#pragma unroll
    for (int j = 0; j < 4; ++j) {
      int gcol = col0 + wn + j * 16 + ml;
#pragma unroll
      for (int r = 0; r < 4; ++r) {
        int grow = row0 + wm + i * 16 + qd * 4 + r;
        if (grow < Nn && gcol < Nn)
          SP[(size_t)grow * Nn + gcol] = acc[i][j][r];
      }
    }
}

// ---------------------------------------------------------------------------
// rowstat: per-row max and 1/sum(exp); one wave per row.
__global__ __launch_bounds__(256) void rowstat(
    const float* __restrict__ SP, float* __restrict__ rmx, float* __restrict__ rinv) {
  int wid = threadIdx.x >> 6, lane = threadIdx.x & 63;
  int n = blockIdx.x * 4 + wid;
  const float* row = SP + (size_t)n * Nn;
  float m = -3.0e38f;
  for (int k = lane * 4; k < Nn; k += 256) {
    float4 v = *(const float4*)(row + k);
    m = fmaxf(m, fmaxf(fmaxf(v.x, v.y), fmaxf(v.z, v.w)));
  }
#pragma unroll
  for (int off = 32; off > 0; off >>= 1) m = fmaxf(m, __shfl_down(m, off, 64));
  m = __shfl(m, 0, 64);
  float s = 0.f;
  for (int k = lane * 4; k < Nn; k += 256) {
    float4 v = *(const float4*)(row + k);
    s += __expf(v.x - m) + __expf(v.y - m) + __expf(v.z - m) + __expf(v.w - m);
  }
#pragma unroll
  for (int off = 32; off > 0; off >>= 1) s += __shfl_down(s, off, 64);
  if (lane == 0) { rmx[n] = m; rinv[n] = 1.0f / s; }
}

// ---------------------------------------------------------------------------
// txsum0: ts0[b,n,f] = sum_k softmax(SP)[n,k] * xts[b,k,f]
__global__ __launch_bounds__(256) void txsum0_k(
    const float* __restrict__ SP, const float* __restrict__ xts,
    const float* __restrict__ rmx, const float* __restrict__ rinv,
    float* __restrict__ ts0, int b) {
  __shared__ float Ws[16][65];
  __shared__ float Xs[64][17];
  int tid = threadIdx.x;
  int n0 = blockIdx.x * 16;
  int r = tid >> 4, f = tid & 15;
  int xr = tid >> 2, xc = (tid & 3) << 2;
  float rm = rmx[n0 + r], ri = rinv[n0 + r];
  float acc = 0.f;
  for (int k0 = 0; k0 < Nn; k0 += 64) {
    int gk4 = k0 + f * 4;
    {
      float4 v = *(const float4*)(SP + (size_t)(n0 + r) * Nn + gk4);  // pad-safe
      Ws[r][f * 4 + 0] = (gk4 + 0 < Nn) ? __expf(v.x - rm) * ri : 0.f;
      Ws[r][f * 4 + 1] = (gk4 + 1 < Nn) ? __expf(v.y - rm) * ri : 0.f;
      Ws[r][f * 4 + 2] = (gk4 + 2 < Nn) ? __expf(v.z - rm) * ri : 0.f;
      Ws[r][f * 4 + 3] = (gk4 + 3 < Nn) ? __expf(v.w - rm) * ri : 0.f;
    }
    int gk = k0 + xr;
    if (gk < Nn) {
      float4 v = *(const float4*)(xts + ((size_t)b * Nn + gk) * 16 + xc);
      Xs[xr][xc + 0] = v.x; Xs[xr][xc + 1] = v.y; Xs[xr][xc + 2] = v.z; Xs[xr][xc + 3] = v.w;
    } else {
      Xs[xr][xc + 0] = 0.f; Xs[xr][xc + 1] = 0.f; Xs[xr][xc + 2] = 0.f; Xs[xr][xc + 3] = 0.f;
    }
    __syncthreads();
#pragma unroll
    for (int kk = 0; kk < 64; ++kk) acc += Ws[r][kk] * Xs[kk][f];
    __syncthreads();
  }
  ts0[((size_t)b * Nn + n0 + r) * 16 + f] = acc;
}

// ---------------------------------------------------------------------------
// cheb: Cout[b,n,f] = scale*sum_m A[n,m]*Bin[b,m,f] - (C0?C0:0)
// one block handles all 4 batches (64 bf-cols) for 16 rows -> A read once/launch
__global__ __launch_bounds__(256) void cheb_k(
    const float* __restrict__ A, const float* __restrict__ Bin,
    const float* __restrict__ C0, float* __restrict__ Cout, float scale) {
  __shared__ float Ws[16][65];
  __shared__ float Xs[64][65];
  int tid = threadIdx.x;
  int n0 = blockIdx.x * 16;
  int r = tid >> 4, cc = (tid & 15) * 4;  // output row r, bf-cols cc..cc+3
  int lm = tid >> 2, lb = tid & 3;        // loader: m-row lm, batch lb
  float a0 = 0.f, a1 = 0.f, a2 = 0.f, a3 = 0.f;
  for (int k0 = 0; k0 < Nn; k0 += 64) {
    // A tile: 16 rows x 64 k
    if (k0 + cc + 3 < Nn) {
      float4 v = *(const float4*)(A + (size_t)(n0 + r) * Nn + k0 + cc);
      Ws[r][cc + 0] = v.x; Ws[r][cc + 1] = v.y; Ws[r][cc + 2] = v.z; Ws[r][cc + 3] = v.w;
    } else {
      for (int q = 0; q < 4; ++q)
        Ws[r][cc + q] = (k0 + cc + q < Nn) ? A[(size_t)(n0 + r) * Nn + k0 + cc + q] : 0.f;
    }
    // Bin tile: 64 m-rows x 64 bf-cols (all 4 batches)
    int gm = k0 + lm;
#pragma unroll
    for (int seg = 0; seg < 4; ++seg) {
      if (gm < Nn) {
        float4 v = *(const float4*)(Bin + (((size_t)lb * Nn + gm) * 16) + seg * 4);
        Xs[lm][lb * 16 + seg * 4 + 0] = v.x; Xs[lm][lb * 16 + seg * 4 + 1] = v.y;
        Xs[lm][lb * 16 + seg * 4 + 2] = v.z; Xs[lm][lb * 16 + seg * 4 + 3] = v.w;
      } else {
        Xs[lm][lb * 16 + seg * 4 + 0] = 0.f; Xs[lm][lb * 16 + seg * 4 + 1] = 0.f;
        Xs[lm][lb * 16 + seg * 4 + 2] = 0.f; Xs[lm][lb * 16 + seg * 4 + 3] = 0.f;
      }
    }
    __syncthreads();
#pragma unroll
    for (int kk = 0; kk < 64; ++kk) {
      float w = Ws[r][kk];
      a0 += w * Xs[kk][cc + 0];
      a1 += w * Xs[kk][cc + 1];
      a2 += w * Xs[kk][cc + 2];
      a3 += w * Xs[kk][cc + 3];
    }
    __syncthreads();
  }
  int b = cc >> 4, f0 = cc & 15;
  size_t idx = (((size_t)b * Nn) + n0 + r) * 16 + f0;
  float4 out = make_float4(a0 * scale, a1 * scale, a2 * scale, a3 * scale);
  if (C0) {
    float4 c = *(const float4*)(C0 + idx);
    out.x -= c.x; out.y -= c.y; out.z -= c.z; out.w -= c.w;
  }
  *(float4*)(Cout + idx) = out;
}

// ---------------------------------------------------------------------------
// K_y: y = (1/16)*sum_k sum_f tsk[n,f]*cw[k,f,o] + base ; accumulate LN stats
__global__ __launch_bounds__(256) void ky_k(
    const float* __restrict__ ts0, const float* __restrict__ ts1,
    const float* __restrict__ ts2, const float* __restrict__ cw,
    const float* __restrict__ base, float* __restrict__ ybuf,
    float* __restrict__ lnacc) {
  __shared__ float T0[256], T1[256], T2[256], CW[768];
  __shared__ float rs[256], rq[256];
  int tid = threadIdx.x;
  int b = blockIdx.y;
  size_t base_i = ((size_t)b * Nn + blockIdx.x * 16) * 16;
  T0[tid] = ts0[base_i + tid];
  T1[tid] = ts1[base_i + tid];
  T2[tid] = ts2[base_i + tid];
  for (int i = tid; i < 768; i += 256) CW[i] = cw[i];
  __syncthreads();
  int r = tid >> 4, o = tid & 15;
  float acc = 0.f;
#pragma unroll
  for (int f2 = 0; f2 < 16; ++f2) {
    acc += T0[r * 16 + f2] * CW[f2 * 16 + o];
    acc += T1[r * 16 + f2] * CW[256 + f2 * 16 + o];
    acc += T2[r * 16 + f2] * CW[512 + f2 * 16 + o];
  }
  float y = acc * 0.0625f + base[base_i + tid];
  ybuf[base_i + tid] = y;
  rs[tid] = y; rq[tid] = y * y;
  __syncthreads();
  for (int s2 = 128; s2 > 0; s2 >>= 1) {
    if (tid < s2) { rs[tid] += rs[tid + s2]; rq[tid] += rq[tid + s2]; }
    __syncthreads();
  }
  if (tid == 0) {
    atomicAdd(&lnacc[b * 2 + 0], rs[0]);
    atomicAdd(&lnacc[b * 2 + 1], rq[0]);
  }
}

// ---------------------------------------------------------------------------
// K_ln: layernorm over (N,O) per batch + relu
__global__ __launch_bounds__(256) void kln_k(
    const float* __restrict__ ybuf, const float* __restrict__ lnacc,
    const float* __restrict__ lg, const float* __restrict__ lb,
    float* __restrict__ outp) {
  int tid = threadIdx.x;
  int b = blockIdx.y;
  size_t i = ((size_t)b * Nn + blockIdx.x * 16) * 16 + tid;
  size_t nz = (size_t)blockIdx.x * 256 + tid;
  const float inv = 1.0f / 64000.0f;
  float s = lnacc[b * 2 + 0], q = lnacc[b * 2 + 1];
  float mean = s * inv;
  float var = q * inv - mean * mean;
  float rstd = rsqrtf(var + 1e-5f);
  float v = (ybuf[i] - mean) * rstd * lg[nz] + lb[nz];
  outp[i] = fmaxf(v, 0.f);
}

// ---------------------------------------------------------------------------
extern "C" void kernel_launch(void* const* d_in, const int* in_sizes, int n_in,
                              void* d_out, int out_size, void* d_ws, size_t ws_size,
                              hipStream_t stream) {
  const float* x   = (const float*)d_in[0];
  const float* lap = (const float*)d_in[1];
  const float* W1  = (const float*)d_in[2];
  const float* W2  = (const float*)d_in[3];
  const float* W3  = (const float*)d_in[4];
  const float* bs  = (const float*)d_in[5];
  const float* Vs  = (const float*)d_in[6];
  const float* U1  = (const float*)d_in[7];
  const float* U2  = (const float*)d_in[8];
  const float* U3  = (const float*)d_in[9];
  const float* be  = (const float*)d_in[10];
  const float* Ve  = (const float*)d_in[11];
  const float* cw  = (const float*)d_in[12];
  const float* tw  = (const float*)d_in[13];
  const float* tb  = (const float*)d_in[14];
  const float* lg  = (const float*)d_in[15];
  const float* lb  = (const float*)d_in[16];
  float* ws = (float*)d_ws;
  float* SP = ws;  // NP floats
  unsigned short* Vhi = (unsigned short*)(ws + (size_t)NP);
  unsigned short* Vlo = Vhi + (size_t)BF_ELEMS;
  unsigned short* PhT = Vlo + (size_t)BF_ELEMS;
  float* xts  = (float*)(PhT + (size_t)BF_ELEMS);
  float* slhs = xts + 256000;
  float* srhs = slhs + 256000;
  float* base = srhs + 256000;
  float* ts0  = base + 256000;
  float* ts1  = ts0 + 256000;
  float* ts2  = ts1 + 256000;
  float* ybuf = ts2 + 256000;
  float* tl   = ybuf + 256000;  // B*16
  float* tr   = tl + 64;
  float* ecol = tr + 64;
  float* rmx  = ecol + 64;  // N
  float* rinv = rmx + 4000;
  float* lnacc = rinv + 4000;  // B*2

  hipMemsetAsync(tl, 0, 128 * sizeof(float), stream);
  hipMemsetAsync(lnacc, 0, 8 * sizeof(float), stream);

  k1_trhs<<<dim3(16, 4), 256, 0, stream>>>(x, U1, U2, U3, tl, tr);
  k2_eattn<<<dim3(4), 256, 0, stream>>>(tl, tr, be, Ve, ecol);
  k3_pern<<<dim3(16, 4), 256, 0, stream>>>(x, ecol, W1, W2, W3, tw, tb,
                                           xts, slhs, srhs, base);
  vconv<<<dim3(15625), 256, 0, stream>>>(Vs, Vhi, Vlo);
  for (int b = 0; b < 4; ++b) {
    gemm1_P<<<dim3(63, 63), 256, 0, stream>>>(slhs, srhs, bs, PhT, b);
    gemm2_mfma<<<dim3(1024), 256, 0, stream>>>(Vhi, Vlo, PhT, SP);
    rowstat<<<dim3(1000), 256, 0, stream>>>(SP, rmx, rinv);
    txsum0_k<<<dim3(250), 256, 0, stream>>>(SP, xts, rmx, rinv, ts0, b);
  }
  cheb_k<<<dim3(250), 256, 0, stream>>>(lap, ts0, nullptr, ts1, 1.0f);
  cheb_k<<<dim3(250), 256, 0, stream>>>(lap, ts1, ts0, ts2, 2.0f);
  ky_k<<<dim3(250, 4), 256, 0, stream>>>(ts0, ts1, ts2, cw, base, ybuf, lnacc);
  kln_k<<<dim3(250, 4), 256, 0, stream>>>(ybuf, lnacc, lg, lb, (float*)d_out);
}

// Round 4
// 1746.962 us; speedup vs baseline: 4.0884x; 1.4845x over previous
//
#include <hip/hip_runtime.h>
#include <math.h>

#define Bc 4
#define Nn 4000
#define NP (16000000 + 4096)
#define BF_ELEMS 16384000  // 4096 rows x 4000 stride (16-bit elems)

typedef _Float16 half8 __attribute__((ext_vector_type(8)));
typedef float f32x4 __attribute__((ext_vector_type(4)));
typedef unsigned short u16x4 __attribute__((ext_vector_type(4)));

static __device__ __forceinline__ unsigned short f2h(float f) {
  _Float16 h = (_Float16)f;
  unsigned short u;
  __builtin_memcpy(&u, &h, 2);
  return u;
}
static __device__ __forceinline__ void gld16(const void* g, void* l) {
  __builtin_amdgcn_global_load_lds(
      (const __attribute__((address_space(1))) unsigned int*)g,
      (__attribute__((address_space(3))) unsigned int*)l, 16, 0, 0);
}

// ---------------------------------------------------------------------------
// K1: t_lhs[b,t] = sum_{n,f} x*U1[n] ; t_rhs[b,t] = sum_{n,f,g} x*U2[g,n]*U3[g]
__global__ __launch_bounds__(256) void k1_trhs(
    const float* __restrict__ x, const float* __restrict__ U1,
    const float* __restrict__ U2, const float* __restrict__ U3,
    float* __restrict__ tl, float* __restrict__ tr) {
  int b = blockIdx.y;
  int n = blockIdx.x * 256 + threadIdx.x;
  float xs[16];
#pragma unroll
  for (int t = 0; t < 16; ++t) xs[t] = 0.f;
  float c1 = 0.f, c2 = 0.f;
  if (n < Nn) {
    const float* xr = x + ((size_t)b * Nn + n) * 256;
    for (int f = 0; f < 16; ++f) {
#pragma unroll
      for (int q = 0; q < 4; ++q) {
        float4 v = *(const float4*)(xr + f * 16 + q * 4);
        xs[q * 4 + 0] += v.x; xs[q * 4 + 1] += v.y;
        xs[q * 4 + 2] += v.z; xs[q * 4 + 3] += v.w;
      }
    }
    c1 = U1[n];
#pragma unroll
    for (int g = 0; g < 16; ++g) c2 += U2[g * Nn + n] * U3[g];
  }
  int lane = threadIdx.x & 63;
#pragma unroll
  for (int t = 0; t < 16; ++t) {
    float v1 = c1 * xs[t];
    float v2 = c2 * xs[t];
#pragma unroll
    for (int off = 32; off > 0; off >>= 1) {
      v1 += __shfl_down(v1, off, 64);
      v2 += __shfl_down(v2, off, 64);
    }
    if (lane == 0) {
      atomicAdd(&tl[b * 16 + t], v1);
      atomicAdd(&tr[b * 16 + t], v2);
    }
  }
}

// ---------------------------------------------------------------------------
// K2: temporal attention, output Ecol[b,s] = sum_t E[b,t,s]
__global__ __launch_bounds__(256) void k2_eattn(
    const float* __restrict__ tl, const float* __restrict__ tr,
    const float* __restrict__ be, const float* __restrict__ Ve,
    float* __restrict__ ecol) {
  int b = blockIdx.x;
  int tid = threadIdx.x;
  __shared__ float sig[256];
  __shared__ float Em[256];
  int s = tid >> 4, r = tid & 15;
  float z = tl[b * 16 + s] * tr[b * 16 + r] + be[s * 16 + r];
  sig[s * 16 + r] = 1.0f / (1.0f + __expf(-z));
  __syncthreads();
  float e = 0.f;
#pragma unroll
  for (int ss = 0; ss < 16; ++ss) e += Ve[s * 16 + ss] * sig[ss * 16 + r];
  Em[s * 16 + r] = e;
  __syncthreads();
  if (tid < 16) {
    float m = -1e30f;
#pragma unroll
    for (int rr = 0; rr < 16; ++rr) m = fmaxf(m, Em[tid * 16 + rr]);
    float ssum = 0.f;
    float ex[16];
#pragma unroll
    for (int rr = 0; rr < 16; ++rr) { ex[rr] = __expf(Em[tid * 16 + rr] - m); ssum += ex[rr]; }
    float inv = 1.0f / ssum;
#pragma unroll
    for (int rr = 0; rr < 16; ++rr) Em[tid * 16 + rr] = ex[rr] * inv;
  }
  __syncthreads();
  if (tid < 16) {
    float c = 0.f;
#pragma unroll
    for (int tt = 0; tt < 16; ++tt) c += Em[tt * 16 + tid];
    ecol[b * 16 + tid] = c;
  }
}

// ---------------------------------------------------------------------------
// K3: per (b,n) contractions over x row
__global__ __launch_bounds__(256) void k3_pern(
    const float* __restrict__ x, const float* __restrict__ ecol,
    const float* __restrict__ W1, const float* __restrict__ W2,
    const float* __restrict__ W3, const float* __restrict__ time_w,
    const float* __restrict__ time_b,
    float* __restrict__ xts, float* __restrict__ slhs,
    float* __restrict__ srhs, float* __restrict__ base) {
  __shared__ float tws[4096];
  __shared__ float W1s[16], W3s[16], Ecs[16], tbs[16], W2s[256];
  int tid = threadIdx.x;
  int b = blockIdx.y;
  for (int i = tid; i < 4096; i += 256) tws[i] = time_w[i];
  W2s[tid] = W2[tid & 255];
  if (tid < 16) {
    W1s[tid] = W1[tid]; W3s[tid] = W3[tid];
    Ecs[tid] = ecol[b * 16 + tid]; tbs[tid] = time_b[tid];
  }
  __syncthreads();
  int n = blockIdx.x * 256 + tid;
  if (n >= Nn) return;
  const float* xr = x + ((size_t)b * Nn + n) * 256;
  float xtsv[16], slv[16], xw3[16], to[16], resid[16];
#pragma unroll
  for (int i = 0; i < 16; ++i) { xtsv[i] = 0; slv[i] = 0; xw3[i] = 0; to[i] = 0; }
  for (int f = 0; f < 16; ++f) {
    float xf[16];
#pragma unroll
    for (int q = 0; q < 4; ++q) {
      float4 v = *(const float4*)(xr + f * 16 + q * 4);
      xf[q * 4 + 0] = v.x; xf[q * 4 + 1] = v.y; xf[q * 4 + 2] = v.z; xf[q * 4 + 3] = v.w;
    }
    float a = 0, c = 0, d = 0;
#pragma unroll
    for (int t2 = 0; t2 < 16; ++t2) {
      a += Ecs[t2] * xf[t2];
      c += W1s[t2] * xf[t2];
      d += W3s[t2] * xf[t2];
    }
    xtsv[f] = a; slv[f] = c; xw3[f] = d; resid[f] = xf[15];
#pragma unroll
    for (int o = 0; o < 16; ++o) {
      float acc = 0;
#pragma unroll
      for (int t2 = 0; t2 < 16; ++t2) acc += tws[o * 256 + f * 16 + t2] * xf[t2];
      to[o] += acc;
    }
  }
  size_t o16 = ((size_t)b * Nn + n) * 16;
#pragma unroll
  for (int g = 0; g < 16; ++g) {
    float acc = 0;
#pragma unroll
    for (int k2 = 0; k2 < 16; ++k2) acc += W2s[g * 16 + k2] * xw3[k2];
    srhs[o16 + g] = acc;
  }
#pragma unroll
  for (int i = 0; i < 16; ++i) {
    xts[o16 + i] = xtsv[i];
    slhs[o16 + i] = slv[i];
    base[o16 + i] = to[i] + tbs[i] + resid[i];
  }
}

// ---------------------------------------------------------------------------
// vconv: Vs fp32 -> fp16 (values in (0,1), fp16-safe; single term)
__global__ __launch_bounds__(256) void vconv(
    const float* __restrict__ Vs, unsigned short* __restrict__ Vh) {
  size_t i = ((size_t)blockIdx.x * 256 + threadIdx.x) * 4;
  float4 v = *(const float4*)(Vs + i);
  u16x4 h;
  h.x = f2h(v.x); h.y = f2h(v.y); h.z = f2h(v.z); h.w = f2h(v.w);
  *(u16x4*)(Vh + i) = h;
}

// ---------------------------------------------------------------------------
// GEMM1: P[m,k] = sigmoid(slhs[b,m]·srhs[b,k] + bs[m,k]); store P^T (fp16)
__global__ __launch_bounds__(256) void gemm1_P(
    const float* __restrict__ slhs, const float* __restrict__ srhs,
    const float* __restrict__ bsm, unsigned short* __restrict__ PhT, int b) {
  __shared__ float Ms[64][17];     // slhs rows (m)
  __shared__ float Cs[64][17];     // srhs rows (k)
  __shared__ float Pt[64][65];     // P[m][k] tile
  int tid = threadIdx.x;
  int m0 = blockIdx.y * 64, k0 = blockIdx.x * 64;
  int lr = tid >> 2, lq = (tid & 3) << 2;
  {
    int gm = m0 + lr; if (gm > Nn - 1) gm = Nn - 1;
    float4 v = *(const float4*)(slhs + ((size_t)b * Nn + gm) * 16 + lq);
    Ms[lr][lq + 0] = v.x; Ms[lr][lq + 1] = v.y; Ms[lr][lq + 2] = v.z; Ms[lr][lq + 3] = v.w;
    int gk = k0 + lr; if (gk > Nn - 1) gk = Nn - 1;
    float4 w = *(const float4*)(srhs + ((size_t)b * Nn + gk) * 16 + lq);
    Cs[lr][lq + 0] = w.x; Cs[lr][lq + 1] = w.y; Cs[lr][lq + 2] = w.z; Cs[lr][lq + 3] = w.w;
  }
  __syncthreads();
  int tx = tid & 15, ty = tid >> 4;
  float acc[4][4] = {};
#pragma unroll
  for (int f = 0; f < 16; ++f) {
    float a4[4], b4[4];
#pragma unroll
    for (int i = 0; i < 4; ++i) a4[i] = Ms[ty * 4 + i][f];
#pragma unroll
    for (int j = 0; j < 4; ++j) b4[j] = Cs[tx * 4 + j][f];
#pragma unroll
    for (int i = 0; i < 4; ++i)
#pragma unroll
      for (int j = 0; j < 4; ++j) acc[i][j] += a4[i] * b4[j];
  }
#pragma unroll
  for (int i = 0; i < 4; ++i) {
    int m = m0 + ty * 4 + i;
    int k = k0 + tx * 4;
    float bv[4] = {0.f, 0.f, 0.f, 0.f};
    if (m < Nn) {
      if (k + 3 < Nn) {
        float4 t = *(const float4*)(bsm + (size_t)m * Nn + k);
        bv[0] = t.x; bv[1] = t.y; bv[2] = t.z; bv[3] = t.w;
      } else {
        for (int j = 0; j < 4; ++j)
          if (k + j < Nn) bv[j] = bsm[(size_t)m * Nn + k + j];
      }
    }
#pragma unroll
    for (int j = 0; j < 4; ++j) {
      float z = acc[i][j] + bv[j];
      Pt[ty * 4 + i][tx * 4 + j] = 1.f / (1.f + __expf(-z));
    }
  }
  __syncthreads();
  // transposed store: PhT[k][m] fp16
#pragma unroll
  for (int i = 0; i < 4; ++i) {
    int kl = ty * 4 + i;
    int ml = tx * 4;
    int gm = m0 + ml;
    u16x4 h;
    h.x = f2h(Pt[ml + 0][kl]);
    h.y = f2h(Pt[ml + 1][kl]);
    h.z = f2h(Pt[ml + 2][kl]);
    h.w = f2h(Pt[ml + 3][kl]);
    size_t off = (size_t)(k0 + kl) * Nn + gm;
    if (gm + 3 < Nn) {
      *(u16x4*)(PhT + off) = h;
    } else {
      unsigned short hv[4] = {h.x, h.y, h.z, h.w};
      for (int q = 0; q < 4; ++q)
        if (gm + q < Nn) PhT[off + q] = hv[q];
    }
  }
}

// ---------------------------------------------------------------------------
// GEMM2, single-term fp16 MFMA: SP[r][c] = sum_n Vh[r][n]*Ph[n][c]
// 128x128 tile, BK=32, 4 waves x 64x64, mfma_f32_16x16x32_f16 (m97 shape).
__global__ __launch_bounds__(256) void gemm2_mfma(
    const unsigned short* __restrict__ Vh, const unsigned short* __restrict__ PhT,
    float* __restrict__ SP) {
  __shared__ unsigned short Ah[128 * 32];
  __shared__ unsigned short Bh[128 * 32];
  int t = threadIdx.x;
  int pid = blockIdx.x;
  int pm = (pid & 7) | ((pid >> 8) << 3);
  int pn = (pid >> 3) & 31;
  int row0 = pm * 128, col0 = pn * 128;

  size_t a_base = (size_t)(row0 + (t >> 2)) * Nn + (t & 3) * 8;
  size_t b_base = (size_t)(col0 + (t >> 2)) * Nn + (t & 3) * 8;

  int lane = t & 63;
  int wid = t >> 6;
  int wm = (wid >> 1) * 64, wn = (wid & 1) * 64;
  int ml = lane & 15, qd = lane >> 4;
  int aoff = (wm + ml) * 32 + qd * 8;
  int boff = (wn + ml) * 32 + qd * 8;

  f32x4 acc[4][4] = {};

  for (int k0 = 0; k0 < Nn; k0 += 32) {
    gld16(Vh + a_base + k0, &Ah[t * 8]);
    gld16(Vh + a_base + (size_t)64 * Nn + k0, &Ah[2048 + t * 8]);
    gld16(PhT + b_base + k0, &Bh[t * 8]);
    gld16(PhT + b_base + (size_t)64 * Nn + k0, &Bh[2048 + t * 8]);
    __syncthreads();
    half8 a_h[4], b_h[4];
#pragma unroll
    for (int i = 0; i < 4; ++i) a_h[i] = *(const half8*)&Ah[aoff + i * 512];
#pragma unroll
    for (int j = 0; j < 4; ++j) b_h[j] = *(const half8*)&Bh[boff + j * 512];
#pragma unroll
    for (int i = 0; i < 4; ++i)
#pragma unroll
      for (int j = 0; j < 4; ++j)
        acc[i][j] = __builtin_amdgcn_mfma_f32_16x16x32_f16(a_h[i], b_h[j], acc[i][j], 0, 0, 0);
    __syncthreads();
  }
  // C/D layout: col = lane&15, row = (lane>>4)*4 + reg  [m89-verified]
#pragma unroll
  for (int i = 0; i < 4; ++i)
#pragma unroll
    for (int j = 0; j < 4; ++j) {
      int gcol = col0 + wn + j * 16 + ml;
#pragma unroll
      for (int r = 0; r < 4; ++r) {
        int grow = row0 + wm + i * 16 + qd * 4 + r;
        if (grow < Nn && gcol < Nn)
          SP[(size_t)grow * Nn + gcol] = acc[i][j][r];
      }
    }
}

// ---------------------------------------------------------------------------
// txsum0 (fused online softmax): ts0[b,n,f] = sum_k softmax(SP)[n,k]*xts[b,k,f]
// 16 rows/block; raw SP segment in regs, tile-max via shfl_xor over 16 f-threads,
// exp'd weights through LDS, running (m,l,acc) rescale.
__global__ __launch_bounds__(256) void txsum0_k(
    const float* __restrict__ SP, const float* __restrict__ xts,
    float* __restrict__ ts0, int b) {
  __shared__ float Ws[16][65];
  __shared__ float Xs[64][17];
  int tid = threadIdx.x;
  int n0 = blockIdx.x * 16;
  int r = tid >> 4, f = tid & 15;
  int lq = f * 4;  // this thread's 4-col segment of row r
  int xr = tid >> 2, xc = (tid & 3) << 2;
  const float* spr = SP + (size_t)(n0 + r) * Nn;
  const float NEG = -3.0e38f;
  float m_run = NEG, l_run = 0.f, acc = 0.f;
  for (int k0 = 0; k0 < Nn; k0 += 64) {
    // load X tile 64x16 to LDS
    int gx = k0 + xr;
    if (gx < Nn) {
      float4 v = *(const float4*)(xts + ((size_t)b * Nn + gx) * 16 + xc);
      Xs[xr][xc + 0] = v.x; Xs[xr][xc + 1] = v.y; Xs[xr][xc + 2] = v.z; Xs[xr][xc + 3] = v.w;
    } else {
      Xs[xr][xc + 0] = 0.f; Xs[xr][xc + 1] = 0.f; Xs[xr][xc + 2] = 0.f; Xs[xr][xc + 3] = 0.f;
    }
    // raw SP segment to regs (masked)
    int gk = k0 + lq;
    float4 v = *(const float4*)(spr + gk);  // pad-safe (SP has +4096 floats)
    float w0 = (gk + 0 < Nn) ? v.x : NEG;
    float w1 = (gk + 1 < Nn) ? v.y : NEG;
    float w2 = (gk + 2 < Nn) ? v.z : NEG;
    float w3 = (gk + 3 < Nn) ? v.w : NEG;
    // tile max across row's 16 threads
    float tm = fmaxf(fmaxf(w0, w1), fmaxf(w2, w3));
#pragma unroll
    for (int mk = 1; mk < 16; mk <<= 1) tm = fmaxf(tm, __shfl_xor(tm, mk, 64));
    float m_new = fmaxf(m_run, tm);
    float scale = __expf(m_run - m_new);
    // exp and write to LDS
    float e0 = __expf(w0 - m_new), e1 = __expf(w1 - m_new);
    float e2 = __expf(w2 - m_new), e3 = __expf(w3 - m_new);
    Ws[r][lq + 0] = e0; Ws[r][lq + 1] = e1; Ws[r][lq + 2] = e2; Ws[r][lq + 3] = e3;
    float lp = e0 + e1 + e2 + e3;
#pragma unroll
    for (int mk = 1; mk < 16; mk <<= 1) lp += __shfl_xor(lp, mk, 64);
    l_run = l_run * scale + lp;
    acc *= scale;
    m_run = m_new;
    __syncthreads();
#pragma unroll
    for (int kk = 0; kk < 64; ++kk) acc += Ws[r][kk] * Xs[kk][f];
    __syncthreads();
  }
  ts0[((size_t)b * Nn + n0 + r) * 16 + f] = acc / l_run;
}

// ---------------------------------------------------------------------------
// cheb: Cout[b,n,f] = scale*sum_m A[n,m]*Bin[b,m,f] - (C0?C0:0)
// one block handles all 4 batches (64 bf-cols) for 16 rows
__global__ __launch_bounds__(256) void cheb_k(
    const float* __restrict__ A, const float* __restrict__ Bin,
    const float* __restrict__ C0, float* __restrict__ Cout, float scale) {
  __shared__ float Ws[16][65];
  __shared__ float Xs[64][65];
  int tid = threadIdx.x;
  int n0 = blockIdx.x * 16;
  int r = tid >> 4, cc = (tid & 15) * 4;
  int lm = tid >> 2, lb = tid & 3;
  float a0 = 0.f, a1 = 0.f, a2 = 0.f, a3 = 0.f;
  for (int k0 = 0; k0 < Nn; k0 += 64) {
    if (k0 + cc + 3 < Nn) {
      float4 v = *(const float4*)(A + (size_t)(n0 + r) * Nn + k0 + cc);
      Ws[r][cc + 0] = v.x; Ws[r][cc + 1] = v.y; Ws[r][cc + 2] = v.z; Ws[r][cc + 3] = v.w;
    } else {
      for (int q = 0; q < 4; ++q)
        Ws[r][cc + q] = (k0 + cc + q < Nn) ? A[(size_t)(n0 + r) * Nn + k0 + cc + q] : 0.f;
    }
    int gm = k0 + lm;
#pragma unroll
    for (int seg = 0; seg < 4; ++seg) {
      if (gm < Nn) {
        float4 v = *(const float4*)(Bin + (((size_t)lb * Nn + gm) * 16) + seg * 4);
        Xs[lm][lb * 16 + seg * 4 + 0] = v.x; Xs[lm][lb * 16 + seg * 4 + 1] = v.y;
        Xs[lm][lb * 16 + seg * 4 + 2] = v.z; Xs[lm][lb * 16 + seg * 4 + 3] = v.w;
      } else {
        Xs[lm][lb * 16 + seg * 4 + 0] = 0.f; Xs[lm][lb * 16 + seg * 4 + 1] = 0.f;
        Xs[lm][lb * 16 + seg * 4 + 2] = 0.f; Xs[lm][lb * 16 + seg * 4 + 3] = 0.f;
      }
    }
    __syncthreads();
#pragma unroll
    for (int kk = 0; kk < 64; ++kk) {
      float w = Ws[r][kk];
      a0 += w * Xs[kk][cc + 0];
      a1 += w * Xs[kk][cc + 1];
      a2 += w * Xs[kk][cc + 2];
      a3 += w * Xs[kk][cc + 3];
    }
    __syncthreads();
  }
  int b = cc >> 4, f0 = cc & 15;
  size_t idx = (((size_t)b * Nn) + n0 + r) * 16 + f0;
  float4 out = make_float4(a0 * scale, a1 * scale, a2 * scale, a3 * scale);
  if (C0) {
    float4 c = *(const float4*)(C0 + idx);
    out.x -= c.x; out.y -= c.y; out.z -= c.z; out.w -= c.w;
  }
  *(float4*)(Cout + idx) = out;
}

// ---------------------------------------------------------------------------
// K_y: y = (1/16)*sum_k sum_f tsk[n,f]*cw[k,f,o] + base ; accumulate LN stats
__global__ __launch_bounds__(256) void ky_k(
    const float* __restrict__ ts0, const float* __restrict__ ts1,
    const float* __restrict__ ts2, const float* __restrict__ cw,
    const float* __restrict__ base, float* __restrict__ ybuf,
    float* __restrict__ lnacc) {
  __shared__ float T0[256], T1[256], T2[256], CW[768];
  __shared__ float rs[256], rq[256];
  int tid = threadIdx.x;
  int b = blockIdx.y;
  size_t base_i = ((size_t)b * Nn + blockIdx.x * 16) * 16;
  T0[tid] = ts0[base_i + tid];
  T1[tid] = ts1[base_i + tid];
  T2[tid] = ts2[base_i + tid];
  for (int i = tid; i < 768; i += 256) CW[i] = cw[i];
  __syncthreads();
  int r = tid >> 4, o = tid & 15;
  float acc = 0.f;
#pragma unroll
  for (int f2 = 0; f2 < 16; ++f2) {
    acc += T0[r * 16 + f2] * CW[f2 * 16 + o];
    acc += T1[r * 16 + f2] * CW[256 + f2 * 16 + o];
    acc += T2[r * 16 + f2] * CW[512 + f2 * 16 + o];
  }
  float y = acc * 0.0625f + base[base_i + tid];
  ybuf[base_i + tid] = y;
  rs[tid] = y; rq[tid] = y * y;
  __syncthreads();
  for (int s2 = 128; s2 > 0; s2 >>= 1) {
    if (tid < s2) { rs[tid] += rs[tid + s2]; rq[tid] += rq[tid + s2]; }
    __syncthreads();
  }
  if (tid == 0) {
    atomicAdd(&lnacc[b * 2 + 0], rs[0]);
    atomicAdd(&lnacc[b * 2 + 1], rq[0]);
  }
}

// ---------------------------------------------------------------------------
// K_ln: layernorm over (N,O) per batch + relu
__global__ __launch_bounds__(256) void kln_k(
    const float* __restrict__ ybuf, const float* __restrict__ lnacc,
    const float* __restrict__ lg, const float* __restrict__ lb,
    float* __restrict__ outp) {
  int tid = threadIdx.x;
  int b = blockIdx.y;
  size_t i = ((size_t)b * Nn + blockIdx.x * 16) * 16 + tid;
  size_t nz = (size_t)blockIdx.x * 256 + tid;
  const float inv = 1.0f / 64000.0f;
  float s = lnacc[b * 2 + 0], q = lnacc[b * 2 + 1];
  float mean = s * inv;
  float var = q * inv - mean * mean;
  float rstd = rsqrtf(var + 1e-5f);
  float v = (ybuf[i] - mean) * rstd * lg[nz] + lb[nz];
  outp[i] = fmaxf(v, 0.f);
}

// ---------------------------------------------------------------------------
extern "C" void kernel_launch(void* const* d_in, const int* in_sizes, int n_in,
                              void* d_out, int out_size, void* d_ws, size_t ws_size,
                              hipStream_t stream) {
  const float* x   = (const float*)d_in[0];
  const float* lap = (const float*)d_in[1];
  const float* W1  = (const float*)d_in[2];
  const float* W2  = (const float*)d_in[3];
  const float* W3  = (const float*)d_in[4];
  const float* bs  = (const float*)d_in[5];
  const float* Vs  = (const float*)d_in[6];
  const float* U1  = (const float*)d_in[7];
  const float* U2  = (const float*)d_in[8];
  const float* U3  = (const float*)d_in[9];
  const float* be  = (const float*)d_in[10];
  const float* Ve  = (const float*)d_in[11];
  const float* cw  = (const float*)d_in[12];
  const float* tw  = (const float*)d_in[13];
  const float* tb  = (const float*)d_in[14];
  const float* lg  = (const float*)d_in[15];
  const float* lb  = (const float*)d_in[16];
  float* ws = (float*)d_ws;
  float* SP = ws;  // NP floats
  unsigned short* Vh  = (unsigned short*)(ws + (size_t)NP);
  unsigned short* PhT = Vh + (size_t)BF_ELEMS;
  float* xts  = (float*)(PhT + (size_t)BF_ELEMS);
  float* slhs = xts + 256000;
  float* srhs = slhs + 256000;
  float* base = srhs + 256000;
  float* ts0  = base + 256000;
  float* ts1  = ts0 + 256000;
  float* ts2  = ts1 + 256000;
  float* ybuf = ts2 + 256000;
  float* tl   = ybuf + 256000;  // B*16
  float* tr   = tl + 64;
  float* ecol = tr + 64;
  float* lnacc = ecol + 64;  // B*2

  hipMemsetAsync(tl, 0, 128 * sizeof(float), stream);
  hipMemsetAsync(lnacc, 0, 8 * sizeof(float), stream);

  k1_trhs<<<dim3(16, 4), 256, 0, stream>>>(x, U1, U2, U3, tl, tr);
  k2_eattn<<<dim3(4), 256, 0, stream>>>(tl, tr, be, Ve, ecol);
  k3_pern<<<dim3(16, 4), 256, 0, stream>>>(x, ecol, W1, W2, W3, tw, tb,
                                           xts, slhs, srhs, base);
  vconv<<<dim3(15625), 256, 0, stream>>>(Vs, Vh);
  for (int b = 0; b < 4; ++b) {
    gemm1_P<<<dim3(63, 63), 256, 0, stream>>>(slhs, srhs, bs, PhT, b);
    gemm2_mfma<<<dim3(1024), 256, 0, stream>>>(Vh, PhT, SP);
    txsum0_k<<<dim3(250), 256, 0, stream>>>(SP, xts, ts0, b);
  }
  cheb_k<<<dim3(250), 256, 0, stream>>>(lap, ts0, nullptr, ts1, 1.0f);
  cheb_k<<<dim3(250), 256, 0, stream>>>(lap, ts1, ts0, ts2, 2.0f);
  ky_k<<<dim3(250, 4), 256, 0, stream>>>(ts0, ts1, ts2, cw, base, ybuf, lnacc);
  kln_k<<<dim3(250, 4), 256, 0, stream>>>(ybuf, lnacc, lg, lb, (float*)d_out);
}

// Round 5
// 1486.522 us; speedup vs baseline: 4.8047x; 1.1752x over previous
//
#include <hip/hip_runtime.h>
#include <math.h>

#define Bc 4
#define Nn 4000
#define NP (16000000 + 4096)
#define BF_ELEMS 16384000  // 4096 rows x 4000 stride (16-bit elems)

typedef _Float16 half8 __attribute__((ext_vector_type(8)));
typedef float f32x4 __attribute__((ext_vector_type(4)));
typedef unsigned short u16x4 __attribute__((ext_vector_type(4)));

static __device__ __forceinline__ unsigned short f2h(float f) {
  _Float16 h = (_Float16)f;
  unsigned short u;
  __builtin_memcpy(&u, &h, 2);
  return u;
}
static __device__ __forceinline__ void gld16(const void* g, void* l) {
  __builtin_amdgcn_global_load_lds(
      (const __attribute__((address_space(1))) unsigned int*)g,
      (__attribute__((address_space(3))) unsigned int*)l, 16, 0, 0);
}

// ---------------------------------------------------------------------------
// K1: t_lhs[b,t] = sum_{n,f} x*U1[n] ; t_rhs[b,t] = sum_{n,f,g} x*U2[g,n]*U3[g]
__global__ __launch_bounds__(256) void k1_trhs(
    const float* __restrict__ x, const float* __restrict__ U1,
    const float* __restrict__ U2, const float* __restrict__ U3,
    float* __restrict__ tl, float* __restrict__ tr) {
  int b = blockIdx.y;
  int n = blockIdx.x * 256 + threadIdx.x;
  float xs[16];
#pragma unroll
  for (int t = 0; t < 16; ++t) xs[t] = 0.f;
  float c1 = 0.f, c2 = 0.f;
  if (n < Nn) {
    const float* xr = x + ((size_t)b * Nn + n) * 256;
    for (int f = 0; f < 16; ++f) {
#pragma unroll
      for (int q = 0; q < 4; ++q) {
        float4 v = *(const float4*)(xr + f * 16 + q * 4);
        xs[q * 4 + 0] += v.x; xs[q * 4 + 1] += v.y;
        xs[q * 4 + 2] += v.z; xs[q * 4 + 3] += v.w;
      }
    }
    c1 = U1[n];
#pragma unroll
    for (int g = 0; g < 16; ++g) c2 += U2[g * Nn + n] * U3[g];
  }
  int lane = threadIdx.x & 63;
#pragma unroll
  for (int t = 0; t < 16; ++t) {
    float v1 = c1 * xs[t];
    float v2 = c2 * xs[t];
#pragma unroll
    for (int off = 32; off > 0; off >>= 1) {
      v1 += __shfl_down(v1, off, 64);
      v2 += __shfl_down(v2, off, 64);
    }
    if (lane == 0) {
      atomicAdd(&tl[b * 16 + t], v1);
      atomicAdd(&tr[b * 16 + t], v2);
    }
  }
}

// ---------------------------------------------------------------------------
// K2: temporal attention, output Ecol[b,s] = sum_t E[b,t,s]
__global__ __launch_bounds__(256) void k2_eattn(
    const float* __restrict__ tl, const float* __restrict__ tr,
    const float* __restrict__ be, const float* __restrict__ Ve,
    float* __restrict__ ecol) {
  int b = blockIdx.x;
  int tid = threadIdx.x;
  __shared__ float sig[256];
  __shared__ float Em[256];
  int s = tid >> 4, r = tid & 15;
  float z = tl[b * 16 + s] * tr[b * 16 + r] + be[s * 16 + r];
  sig[s * 16 + r] = 1.0f / (1.0f + __expf(-z));
  __syncthreads();
  float e = 0.f;
#pragma unroll
  for (int ss = 0; ss < 16; ++ss) e += Ve[s * 16 + ss] * sig[ss * 16 + r];
  Em[s * 16 + r] = e;
  __syncthreads();
  if (tid < 16) {
    float m = -1e30f;
#pragma unroll
    for (int rr = 0; rr < 16; ++rr) m = fmaxf(m, Em[tid * 16 + rr]);
    float ssum = 0.f;
    float ex[16];
#pragma unroll
    for (int rr = 0; rr < 16; ++rr) { ex[rr] = __expf(Em[tid * 16 + rr] - m); ssum += ex[rr]; }
    float inv = 1.0f / ssum;
#pragma unroll
    for (int rr = 0; rr < 16; ++rr) Em[tid * 16 + rr] = ex[rr] * inv;
  }
  __syncthreads();
  if (tid < 16) {
    float c = 0.f;
#pragma unroll
    for (int tt = 0; tt < 16; ++tt) c += Em[tt * 16 + tid];
    ecol[b * 16 + tid] = c;
  }
}

// ---------------------------------------------------------------------------
// K3: per (b,n) contractions over x row
__global__ __launch_bounds__(256) void k3_pern(
    const float* __restrict__ x, const float* __restrict__ ecol,
    const float* __restrict__ W1, const float* __restrict__ W2,
    const float* __restrict__ W3, const float* __restrict__ time_w,
    const float* __restrict__ time_b,
    float* __restrict__ xts, float* __restrict__ slhs,
    float* __restrict__ srhs, float* __restrict__ base) {
  __shared__ float tws[4096];
  __shared__ float W1s[16], W3s[16], Ecs[16], tbs[16], W2s[256];
  int tid = threadIdx.x;
  int b = blockIdx.y;
  for (int i = tid; i < 4096; i += 256) tws[i] = time_w[i];
  W2s[tid] = W2[tid & 255];
  if (tid < 16) {
    W1s[tid] = W1[tid]; W3s[tid] = W3[tid];
    Ecs[tid] = ecol[b * 16 + tid]; tbs[tid] = time_b[tid];
  }
  __syncthreads();
  int n = blockIdx.x * 256 + tid;
  if (n >= Nn) return;
  const float* xr = x + ((size_t)b * Nn + n) * 256;
  float xtsv[16], slv[16], xw3[16], to[16], resid[16];
#pragma unroll
  for (int i = 0; i < 16; ++i) { xtsv[i] = 0; slv[i] = 0; xw3[i] = 0; to[i] = 0; }
  for (int f = 0; f < 16; ++f) {
    float xf[16];
#pragma unroll
    for (int q = 0; q < 4; ++q) {
      float4 v = *(const float4*)(xr + f * 16 + q * 4);
      xf[q * 4 + 0] = v.x; xf[q * 4 + 1] = v.y; xf[q * 4 + 2] = v.z; xf[q * 4 + 3] = v.w;
    }
    float a = 0, c = 0, d = 0;
#pragma unroll
    for (int t2 = 0; t2 < 16; ++t2) {
      a += Ecs[t2] * xf[t2];
      c += W1s[t2] * xf[t2];
      d += W3s[t2] * xf[t2];
    }
    xtsv[f] = a; slv[f] = c; xw3[f] = d; resid[f] = xf[15];
#pragma unroll
    for (int o = 0; o < 16; ++o) {
      float acc = 0;
#pragma unroll
      for (int t2 = 0; t2 < 16; ++t2) acc += tws[o * 256 + f * 16 + t2] * xf[t2];
      to[o] += acc;
    }
  }
  size_t o16 = ((size_t)b * Nn + n) * 16;
#pragma unroll
  for (int g = 0; g < 16; ++g) {
    float acc = 0;
#pragma unroll
    for (int k2 = 0; k2 < 16; ++k2) acc += W2s[g * 16 + k2] * xw3[k2];
    srhs[o16 + g] = acc;
  }
#pragma unroll
  for (int i = 0; i < 16; ++i) {
    xts[o16 + i] = xtsv[i];
    slhs[o16 + i] = slv[i];
    base[o16 + i] = to[i] + tbs[i] + resid[i];
  }
}

// ---------------------------------------------------------------------------
// fconv: fp32 -> fp16 bulk convert (grid*256*4 elems)
__global__ __launch_bounds__(256) void fconv(
    const float* __restrict__ src, unsigned short* __restrict__ dst) {
  size_t i = ((size_t)blockIdx.x * 256 + threadIdx.x) * 4;
  float4 v = *(const float4*)(src + i);
  u16x4 h;
  h.x = f2h(v.x); h.y = f2h(v.y); h.z = f2h(v.z); h.w = f2h(v.w);
  *(u16x4*)(dst + i) = h;
}

// ---------------------------------------------------------------------------
// tsconv: ts[b][n][f] fp32 -> tsT[(b*16+f)][n] fp16 (B-operand for chebm)
__global__ __launch_bounds__(256) void tsconv(
    const float* __restrict__ ts, unsigned short* __restrict__ tsT) {
  int n = blockIdx.x * 256 + threadIdx.x;
  int col = blockIdx.y;  // 0..63 = (b<<4)|f
  if (n >= Nn) return;
  int b = col >> 4, f = col & 15;
  tsT[(size_t)col * Nn + n] = f2h(ts[((size_t)b * Nn + n) * 16 + f]);
}

// ---------------------------------------------------------------------------
// GEMM1: P[m,k] = sigmoid(slhs[b,m]·srhs[b,k] + bs[m,k]); store P^T (fp16)
__global__ __launch_bounds__(256) void gemm1_P(
    const float* __restrict__ slhs, const float* __restrict__ srhs,
    const float* __restrict__ bsm, unsigned short* __restrict__ PhT, int b) {
  __shared__ float Ms[64][17];
  __shared__ float Cs[64][17];
  __shared__ float Pt[64][65];
  int tid = threadIdx.x;
  int m0 = blockIdx.y * 64, k0 = blockIdx.x * 64;
  int lr = tid >> 2, lq = (tid & 3) << 2;
  {
    int gm = m0 + lr; if (gm > Nn - 1) gm = Nn - 1;
    float4 v = *(const float4*)(slhs + ((size_t)b * Nn + gm) * 16 + lq);
    Ms[lr][lq + 0] = v.x; Ms[lr][lq + 1] = v.y; Ms[lr][lq + 2] = v.z; Ms[lr][lq + 3] = v.w;
    int gk = k0 + lr; if (gk > Nn - 1) gk = Nn - 1;
    float4 w = *(const float4*)(srhs + ((size_t)b * Nn + gk) * 16 + lq);
    Cs[lr][lq + 0] = w.x; Cs[lr][lq + 1] = w.y; Cs[lr][lq + 2] = w.z; Cs[lr][lq + 3] = w.w;
  }
  __syncthreads();
  int tx = tid & 15, ty = tid >> 4;
  float acc[4][4] = {};
#pragma unroll
  for (int f = 0; f < 16; ++f) {
    float a4[4], b4[4];
#pragma unroll
    for (int i = 0; i < 4; ++i) a4[i] = Ms[ty * 4 + i][f];
#pragma unroll
    for (int j = 0; j < 4; ++j) b4[j] = Cs[tx * 4 + j][f];
#pragma unroll
    for (int i = 0; i < 4; ++i)
#pragma unroll
      for (int j = 0; j < 4; ++j) acc[i][j] += a4[i] * b4[j];
  }
#pragma unroll
  for (int i = 0; i < 4; ++i) {
    int m = m0 + ty * 4 + i;
    int k = k0 + tx * 4;
    float bv[4] = {0.f, 0.f, 0.f, 0.f};
    if (m < Nn) {
      if (k + 3 < Nn) {
        float4 t = *(const float4*)(bsm + (size_t)m * Nn + k);
        bv[0] = t.x; bv[1] = t.y; bv[2] = t.z; bv[3] = t.w;
      } else {
        for (int j = 0; j < 4; ++j)
          if (k + j < Nn) bv[j] = bsm[(size_t)m * Nn + k + j];
      }
    }
#pragma unroll
    for (int j = 0; j < 4; ++j) {
      float z = acc[i][j] + bv[j];
      Pt[ty * 4 + i][tx * 4 + j] = 1.f / (1.f + __expf(-z));
    }
  }
  __syncthreads();
#pragma unroll
  for (int i = 0; i < 4; ++i) {
    int kl = ty * 4 + i;
    int ml = tx * 4;
    int gm = m0 + ml;
    u16x4 h;
    h.x = f2h(Pt[ml + 0][kl]);
    h.y = f2h(Pt[ml + 1][kl]);
    h.z = f2h(Pt[ml + 2][kl]);
    h.w = f2h(Pt[ml + 3][kl]);
    size_t off = (size_t)(k0 + kl) * Nn + gm;
    if (gm + 3 < Nn) {
      *(u16x4*)(PhT + off) = h;
    } else {
      unsigned short hv[4] = {h.x, h.y, h.z, h.w};
      for (int q = 0; q < 4; ++q)
        if (gm + q < Nn) PhT[off + q] = hv[q];
    }
  }
}

// ---------------------------------------------------------------------------
// GEMM2, single-term fp16 MFMA: SP[r][c] = sum_n Vh[r][n]*Ph[n][c]
// 128x128 tile, BK=32, 4 waves x 64x64, mfma_f32_16x16x32_f16.
__global__ __launch_bounds__(256) void gemm2_mfma(
    const unsigned short* __restrict__ Vh, const unsigned short* __restrict__ PhT,
    float* __restrict__ SP) {
  __shared__ unsigned short Ah[128 * 32];
  __shared__ unsigned short Bh[128 * 32];
  int t = threadIdx.x;
  int pid = blockIdx.x;
  int pm = (pid & 7) | ((pid >> 8) << 3);
  int pn = (pid >> 3) & 31;
  int row0 = pm * 128, col0 = pn * 128;

  size_t a_base = (size_t)(row0 + (t >> 2)) * Nn + (t & 3) * 8;
  size_t b_base = (size_t)(col0 + (t >> 2)) * Nn + (t & 3) * 8;

  int lane = t & 63;
  int wid = t >> 6;
  int wm = (wid >> 1) * 64, wn = (wid & 1) * 64;
  int ml = lane & 15, qd = lane >> 4;
  int aoff = (wm + ml) * 32 + qd * 8;
  int boff = (wn + ml) * 32 + qd * 8;

  f32x4 acc[4][4] = {};

  for (int k0 = 0; k0 < Nn; k0 += 32) {
    gld16(Vh + a_base + k0, &Ah[t * 8]);
    gld16(Vh + a_base + (size_t)64 * Nn + k0, &Ah[2048 + t * 8]);
    gld16(PhT + b_base + k0, &Bh[t * 8]);
    gld16(PhT + b_base + (size_t)64 * Nn + k0, &Bh[2048 + t * 8]);
    __syncthreads();
    half8 a_h[4], b_h[4];
#pragma unroll
    for (int i = 0; i < 4; ++i) a_h[i] = *(const half8*)&Ah[aoff + i * 512];
#pragma unroll
    for (int j = 0; j < 4; ++j) b_h[j] = *(const half8*)&Bh[boff + j * 512];
#pragma unroll
    for (int i = 0; i < 4; ++i)
#pragma unroll
      for (int j = 0; j < 4; ++j)
        acc[i][j] = __builtin_amdgcn_mfma_f32_16x16x32_f16(a_h[i], b_h[j], acc[i][j], 0, 0, 0);
    __syncthreads();
  }
#pragma unroll
  for (int i = 0; i < 4; ++i)
#pragma unroll
    for (int j = 0; j < 4; ++j) {
      int gcol = col0 + wn + j * 16 + ml;
#pragma unroll
      for (int r = 0; r < 4; ++r) {
        int grow = row0 + wm + i * 16 + qd * 4 + r;
        if (grow < Nn && gcol < Nn)
          SP[(size_t)grow * Nn + gcol] = acc[i][j][r];
      }
    }
}

// ---------------------------------------------------------------------------
// rowstat: per-row max and 1/sum(exp); one wave per row.
__global__ __launch_bounds__(256) void rowstat(
    const float* __restrict__ SP, float* __restrict__ rmx, float* __restrict__ rinv) {
  int wid = threadIdx.x >> 6, lane = threadIdx.x & 63;
  int n = blockIdx.x * 4 + wid;
  const float* row = SP + (size_t)n * Nn;
  float m = -3.0e38f;
  for (int k = lane * 4; k < Nn; k += 256) {
    float4 v = *(const float4*)(row + k);
    m = fmaxf(m, fmaxf(fmaxf(v.x, v.y), fmaxf(v.z, v.w)));
  }
#pragma unroll
  for (int off = 32; off > 0; off >>= 1) m = fmaxf(m, __shfl_down(m, off, 64));
  m = __shfl(m, 0, 64);
  float s = 0.f;
  for (int k = lane * 4; k < Nn; k += 256) {
    float4 v = *(const float4*)(row + k);
    s += __expf(v.x - m) + __expf(v.y - m) + __expf(v.z - m) + __expf(v.w - m);
  }
#pragma unroll
  for (int off = 32; off > 0; off >>= 1) s += __shfl_down(s, off, 64);
  if (lane == 0) { rmx[n] = m; rinv[n] = 1.0f / s; }
}

// ---------------------------------------------------------------------------
// txsum (split-K): partial ts0[b,n,f] += sum_{k in chunk} w[n,k]*xts[b,k,f]
// grid (250 row-blocks, 4 k-chunks); exact weights from rowstat; fp32 atomics.
__global__ __launch_bounds__(256) void txsum_sp(
    const float* __restrict__ SP, const float* __restrict__ xts,
    const float* __restrict__ rmx, const float* __restrict__ rinv,
    float* __restrict__ ts0, int b) {
  __shared__ float Ws[16][65];
  __shared__ float Xs[64][17];
  int tid = threadIdx.x;
  int n0 = blockIdx.x * 16;
  int kbase = blockIdx.y * 1000, kend = kbase + 1000;
  int r = tid >> 4, f = tid & 15;
  int lq = f * 4;
  int xr = tid >> 2, xc = (tid & 3) << 2;
  const float* spr = SP + (size_t)(n0 + r) * Nn;
  float rm = rmx[n0 + r], ri = rinv[n0 + r];
  float acc = 0.f;
  for (int k0 = kbase; k0 < kend; k0 += 64) {
    int gx = k0 + xr;
    if (gx < kend) {
      float4 v = *(const float4*)(xts + ((size_t)b * Nn + gx) * 16 + xc);
      Xs[xr][xc + 0] = v.x; Xs[xr][xc + 1] = v.y; Xs[xr][xc + 2] = v.z; Xs[xr][xc + 3] = v.w;
    } else {
      Xs[xr][xc + 0] = 0.f; Xs[xr][xc + 1] = 0.f; Xs[xr][xc + 2] = 0.f; Xs[xr][xc + 3] = 0.f;
    }
    int gk = k0 + lq;
    float4 v = *(const float4*)(spr + gk);  // pad-safe
    Ws[r][lq + 0] = (gk + 0 < kend) ? __expf(v.x - rm) * ri : 0.f;
    Ws[r][lq + 1] = (gk + 1 < kend) ? __expf(v.y - rm) * ri : 0.f;
    Ws[r][lq + 2] = (gk + 2 < kend) ? __expf(v.z - rm) * ri : 0.f;
    Ws[r][lq + 3] = (gk + 3 < kend) ? __expf(v.w - rm) * ri : 0.f;
    __syncthreads();
#pragma unroll
    for (int kk = 0; kk < 64; ++kk) acc += Ws[r][kk] * Xs[kk][f];
    __syncthreads();
  }
  atomicAdd(&ts0[((size_t)b * Nn + n0 + r) * 16 + f], acc);
}

// ---------------------------------------------------------------------------
// chebm (MFMA): Cout[(c>>4)*Nn+row][c&15] = scale*sum_k lapH[row][k]*tsT[c][k]
//               - (C0 ? C0 : 0)
// M=64 rows/block (grid 63), N=64 cols (4 batches x 16 f), BK=32,
// 4 waves x 32x32, mfma_f32_16x16x32_f16.
__global__ __launch_bounds__(256) void chebm(
    const unsigned short* __restrict__ lapH, const unsigned short* __restrict__ tsT,
    const float* __restrict__ C0, float* __restrict__ Cout, float scale) {
  __shared__ unsigned short Ah[64 * 32];
  __shared__ unsigned short Bh[64 * 32];
  int t = threadIdx.x;
  int row0 = blockIdx.x * 64;
  int arow = row0 + (t >> 2); if (arow > Nn - 1) arow = Nn - 1;
  size_t a_base = (size_t)arow * Nn + (t & 3) * 8;
  size_t b_base = (size_t)(t >> 2) * Nn + (t & 3) * 8;

  int lane = t & 63;
  int wid = t >> 6;
  int wm = (wid >> 1) * 32, wn = (wid & 1) * 32;
  int ml = lane & 15, qd = lane >> 4;
  int aoff = (wm + ml) * 32 + qd * 8;
  int boff = (wn + ml) * 32 + qd * 8;

  f32x4 acc[2][2] = {};

  for (int k0 = 0; k0 < Nn; k0 += 32) {
    gld16(lapH + a_base + k0, &Ah[t * 8]);
    gld16(tsT + b_base + k0, &Bh[t * 8]);
    __syncthreads();
    half8 a_h[2], b_h[2];
#pragma unroll
    for (int i = 0; i < 2; ++i) a_h[i] = *(const half8*)&Ah[aoff + i * 512];
#pragma unroll
    for (int j = 0; j < 2; ++j) b_h[j] = *(const half8*)&Bh[boff + j * 512];
#pragma unroll
    for (int i = 0; i < 2; ++i)
#pragma unroll
      for (int j = 0; j < 2; ++j)
        acc[i][j] = __builtin_amdgcn_mfma_f32_16x16x32_f16(a_h[i], b_h[j], acc[i][j], 0, 0, 0);
    __syncthreads();
  }
#pragma unroll
  for (int i = 0; i < 2; ++i)
#pragma unroll
    for (int j = 0; j < 2; ++j) {
      int gcol = wn + j * 16 + ml;  // 0..63 = (b<<4)|f
      int b = gcol >> 4, f = gcol & 15;
#pragma unroll
      for (int r = 0; r < 4; ++r) {
        int grow = row0 + wm + i * 16 + qd * 4 + r;
        if (grow < Nn) {
          size_t idx = ((size_t)b * Nn + grow) * 16 + f;
          float v = scale * acc[i][j][r];
          if (C0) v -= C0[idx];
          Cout[idx] = v;
        }
      }
    }
}

// ---------------------------------------------------------------------------
// K_y: y = (1/16)*sum_k sum_f tsk[n,f]*cw[k,f,o] + base ; accumulate LN stats
__global__ __launch_bounds__(256) void ky_k(
    const float* __restrict__ ts0, const float* __restrict__ ts1,
    const float* __restrict__ ts2, const float* __restrict__ cw,
    const float* __restrict__ base, float* __restrict__ ybuf,
    float* __restrict__ lnacc) {
  __shared__ float T0[256], T1[256], T2[256], CW[768];
  __shared__ float rs[256], rq[256];
  int tid = threadIdx.x;
  int b = blockIdx.y;
  size_t base_i = ((size_t)b * Nn + blockIdx.x * 16) * 16;
  T0[tid] = ts0[base_i + tid];
  T1[tid] = ts1[base_i + tid];
  T2[tid] = ts2[base_i + tid];
  for (int i = tid; i < 768; i += 256) CW[i] = cw[i];
  __syncthreads();
  int r = tid >> 4, o = tid & 15;
  float acc = 0.f;
#pragma unroll
  for (int f2 = 0; f2 < 16; ++f2) {
    acc += T0[r * 16 + f2] * CW[f2 * 16 + o];
    acc += T1[r * 16 + f2] * CW[256 + f2 * 16 + o];
    acc += T2[r * 16 + f2] * CW[512 + f2 * 16 + o];
  }
  float y = acc * 0.0625f + base[base_i + tid];
  ybuf[base_i + tid] = y;
  rs[tid] = y; rq[tid] = y * y;
  __syncthreads();
  for (int s2 = 128; s2 > 0; s2 >>= 1) {
    if (tid < s2) { rs[tid] += rs[tid + s2]; rq[tid] += rq[tid + s2]; }
    __syncthreads();
  }
  if (tid == 0) {
    atomicAdd(&lnacc[b * 2 + 0], rs[0]);
    atomicAdd(&lnacc[b * 2 + 1], rq[0]);
  }
}

// ---------------------------------------------------------------------------
// K_ln: layernorm over (N,O) per batch + relu
__global__ __launch_bounds__(256) void kln_k(
    const float* __restrict__ ybuf, const float* __restrict__ lnacc,
    const float* __restrict__ lg, const float* __restrict__ lb,
    float* __restrict__ outp) {
  int tid = threadIdx.x;
  int b = blockIdx.y;
  size_t i = ((size_t)b * Nn + blockIdx.x * 16) * 16 + tid;
  size_t nz = (size_t)blockIdx.x * 256 + tid;
  const float inv = 1.0f / 64000.0f;
  float s = lnacc[b * 2 + 0], q = lnacc[b * 2 + 1];
  float mean = s * inv;
  float var = q * inv - mean * mean;
  float rstd = rsqrtf(var + 1e-5f);
  float v = (ybuf[i] - mean) * rstd * lg[nz] + lb[nz];
  outp[i] = fmaxf(v, 0.f);
}

// ---------------------------------------------------------------------------
extern "C" void kernel_launch(void* const* d_in, const int* in_sizes, int n_in,
                              void* d_out, int out_size, void* d_ws, size_t ws_size,
                              hipStream_t stream) {
  const float* x   = (const float*)d_in[0];
  const float* lap = (const float*)d_in[1];
  const float* W1  = (const float*)d_in[2];
  const float* W2  = (const float*)d_in[3];
  const float* W3  = (const float*)d_in[4];
  const float* bs  = (const float*)d_in[5];
  const float* Vs  = (const float*)d_in[6];
  const float* U1  = (const float*)d_in[7];
  const float* U2  = (const float*)d_in[8];
  const float* U3  = (const float*)d_in[9];
  const float* be  = (const float*)d_in[10];
  const float* Ve  = (const float*)d_in[11];
  const float* cw  = (const float*)d_in[12];
  const float* tw  = (const float*)d_in[13];
  const float* tb  = (const float*)d_in[14];
  const float* lg  = (const float*)d_in[15];
  const float* lb  = (const float*)d_in[16];
  float* ws = (float*)d_ws;
  float* SP = ws;  // NP floats
  unsigned short* Vh   = (unsigned short*)(ws + (size_t)NP);
  unsigned short* PhT  = Vh + (size_t)BF_ELEMS;
  unsigned short* lapH = PhT + (size_t)BF_ELEMS;
  unsigned short* tsT  = lapH + (size_t)BF_ELEMS;   // 64 x 4000 fp16
  float* xts  = (float*)(tsT + 64 * Nn + 64);
  float* slhs = xts + 256000;
  float* srhs = slhs + 256000;
  float* base = srhs + 256000;
  float* ts0  = base + 256000;
  float* ts1  = ts0 + 256000;
  float* ts2  = ts1 + 256000;
  float* ybuf = ts2 + 256000;
  float* tl   = ybuf + 256000;  // B*16
  float* tr   = tl + 64;
  float* ecol = tr + 64;
  float* rmx  = ecol + 64;  // N
  float* rinv = rmx + 4000;
  float* lnacc = rinv + 4000;  // B*2

  hipMemsetAsync(tl, 0, 128 * sizeof(float), stream);
  hipMemsetAsync(lnacc, 0, 8 * sizeof(float), stream);
  hipMemsetAsync(ts0, 0, 256000 * sizeof(float), stream);

  k1_trhs<<<dim3(16, 4), 256, 0, stream>>>(x, U1, U2, U3, tl, tr);
  k2_eattn<<<dim3(4), 256, 0, stream>>>(tl, tr, be, Ve, ecol);
  k3_pern<<<dim3(16, 4), 256, 0, stream>>>(x, ecol, W1, W2, W3, tw, tb,
                                           xts, slhs, srhs, base);
  fconv<<<dim3(15625), 256, 0, stream>>>(Vs, Vh);
  fconv<<<dim3(15625), 256, 0, stream>>>(lap, lapH);
  for (int b = 0; b < 4; ++b) {
    gemm1_P<<<dim3(63, 63), 256, 0, stream>>>(slhs, srhs, bs, PhT, b);
    gemm2_mfma<<<dim3(1024), 256, 0, stream>>>(Vh, PhT, SP);
    rowstat<<<dim3(1000), 256, 0, stream>>>(SP, rmx, rinv);
    txsum_sp<<<dim3(250, 4), 256, 0, stream>>>(SP, xts, rmx, rinv, ts0, b);
  }
  tsconv<<<dim3(16, 64), 256, 0, stream>>>(ts0, tsT);
  chebm<<<dim3(63), 256, 0, stream>>>(lapH, tsT, nullptr, ts1, 1.0f);
  tsconv<<<dim3(16, 64), 256, 0, stream>>>(ts1, tsT);
  chebm<<<dim3(63), 256, 0, stream>>>(lapH, tsT, ts0, ts2, 2.0f);
  ky_k<<<dim3(250, 4), 256, 0, stream>>>(ts0, ts1, ts2, cw, base, ybuf, lnacc);
  kln_k<<<dim3(250, 4), 256, 0, stream>>>(ybuf, lnacc, lg, lb, (float*)d_out);
}

// Round 7
// 1421.986 us; speedup vs baseline: 5.0227x; 1.0454x over previous
//
#include <hip/hip_runtime.h>
#include <math.h>

#define Bc 4
#define Nn 4000
#define KS 4096              // padded K stride for gemm2 operands
#define NP (16000000 + 4096)

typedef _Float16 half8 __attribute__((ext_vector_type(8)));
typedef float f32x4 __attribute__((ext_vector_type(4)));
typedef unsigned short u16x4 __attribute__((ext_vector_type(4)));

static __device__ __forceinline__ unsigned short f2h(float f) {
  _Float16 h = (_Float16)f;
  unsigned short u;
  __builtin_memcpy(&u, &h, 2);
  return u;
}
static __device__ __forceinline__ float h2f(unsigned short u) {
  _Float16 h;
  __builtin_memcpy(&h, &u, 2);
  return (float)h;
}
static __device__ __forceinline__ void gld16(const void* g, void* l) {
  __builtin_amdgcn_global_load_lds(
      (const __attribute__((address_space(1))) unsigned int*)g,
      (__attribute__((address_space(3))) unsigned int*)l, 16, 0, 0);
}

// ---------------------------------------------------------------------------
// K1: t_lhs[b,t] = sum_{n,f} x*U1[n] ; t_rhs[b,t] = sum_{n,f,g} x*U2[g,n]*U3[g]
__global__ __launch_bounds__(256) void k1_trhs(
    const float* __restrict__ x, const float* __restrict__ U1,
    const float* __restrict__ U2, const float* __restrict__ U3,
    float* __restrict__ tl, float* __restrict__ tr) {
  int b = blockIdx.y;
  int n = blockIdx.x * 256 + threadIdx.x;
  float xs[16];
#pragma unroll
  for (int t = 0; t < 16; ++t) xs[t] = 0.f;
  float c1 = 0.f, c2 = 0.f;
  if (n < Nn) {
    const float* xr = x + ((size_t)b * Nn + n) * 256;
    for (int f = 0; f < 16; ++f) {
#pragma unroll
      for (int q = 0; q < 4; ++q) {
        float4 v = *(const float4*)(xr + f * 16 + q * 4);
        xs[q * 4 + 0] += v.x; xs[q * 4 + 1] += v.y;
        xs[q * 4 + 2] += v.z; xs[q * 4 + 3] += v.w;
      }
    }
    c1 = U1[n];
#pragma unroll
    for (int g = 0; g < 16; ++g) c2 += U2[g * Nn + n] * U3[g];
  }
  int lane = threadIdx.x & 63;
#pragma unroll
  for (int t = 0; t < 16; ++t) {
    float v1 = c1 * xs[t];
    float v2 = c2 * xs[t];
#pragma unroll
    for (int off = 32; off > 0; off >>= 1) {
      v1 += __shfl_down(v1, off, 64);
      v2 += __shfl_down(v2, off, 64);
    }
    if (lane == 0) {
      atomicAdd(&tl[b * 16 + t], v1);
      atomicAdd(&tr[b * 16 + t], v2);
    }
  }
}

// ---------------------------------------------------------------------------
// K2: temporal attention, output Ecol[b,s] = sum_t E[b,t,s]
__global__ __launch_bounds__(256) void k2_eattn(
    const float* __restrict__ tl, const float* __restrict__ tr,
    const float* __restrict__ be, const float* __restrict__ Ve,
    float* __restrict__ ecol) {
  int b = blockIdx.x;
  int tid = threadIdx.x;
  __shared__ float sig[256];
  __shared__ float Em[256];
  int s = tid >> 4, r = tid & 15;
  float z = tl[b * 16 + s] * tr[b * 16 + r] + be[s * 16 + r];
  sig[s * 16 + r] = 1.0f / (1.0f + __expf(-z));
  __syncthreads();
  float e = 0.f;
#pragma unroll
  for (int ss = 0; ss < 16; ++ss) e += Ve[s * 16 + ss] * sig[ss * 16 + r];
  Em[s * 16 + r] = e;
  __syncthreads();
  if (tid < 16) {
    float m = -1e30f;
#pragma unroll
    for (int rr = 0; rr < 16; ++rr) m = fmaxf(m, Em[tid * 16 + rr]);
    float ssum = 0.f;
    float ex[16];
#pragma unroll
    for (int rr = 0; rr < 16; ++rr) { ex[rr] = __expf(Em[tid * 16 + rr] - m); ssum += ex[rr]; }
    float inv = 1.0f / ssum;
#pragma unroll
    for (int rr = 0; rr < 16; ++rr) Em[tid * 16 + rr] = ex[rr] * inv;
  }
  __syncthreads();
  if (tid < 16) {
    float c = 0.f;
#pragma unroll
    for (int tt = 0; tt < 16; ++tt) c += Em[tt * 16 + tid];
    ecol[b * 16 + tid] = c;
  }
}

// ---------------------------------------------------------------------------
// K3: per (b,n) contractions over x row
__global__ __launch_bounds__(256) void k3_pern(
    const float* __restrict__ x, const float* __restrict__ ecol,
    const float* __restrict__ W1, const float* __restrict__ W2,
    const float* __restrict__ W3, const float* __restrict__ time_w,
    const float* __restrict__ time_b,
    float* __restrict__ xts, float* __restrict__ slhs,
    float* __restrict__ srhs, float* __restrict__ base) {
  __shared__ float tws[4096];
  __shared__ float W1s[16], W3s[16], Ecs[16], tbs[16], W2s[256];
  int tid = threadIdx.x;
  int b = blockIdx.y;
  for (int i = tid; i < 4096; i += 256) tws[i] = time_w[i];
  W2s[tid] = W2[tid & 255];
  if (tid < 16) {
    W1s[tid] = W1[tid]; W3s[tid] = W3[tid];
    Ecs[tid] = ecol[b * 16 + tid]; tbs[tid] = time_b[tid];
  }
  __syncthreads();
  int n = blockIdx.x * 256 + tid;
  if (n >= Nn) return;
  const float* xr = x + ((size_t)b * Nn + n) * 256;
  float xtsv[16], slv[16], xw3[16], to[16], resid[16];
#pragma unroll
  for (int i = 0; i < 16; ++i) { xtsv[i] = 0; slv[i] = 0; xw3[i] = 0; to[i] = 0; }
  for (int f = 0; f < 16; ++f) {
    float xf[16];
#pragma unroll
    for (int q = 0; q < 4; ++q) {
      float4 v = *(const float4*)(xr + f * 16 + q * 4);
      xf[q * 4 + 0] = v.x; xf[q * 4 + 1] = v.y; xf[q * 4 + 2] = v.z; xf[q * 4 + 3] = v.w;
    }
    float a = 0, c = 0, d = 0;
#pragma unroll
    for (int t2 = 0; t2 < 16; ++t2) {
      a += Ecs[t2] * xf[t2];
      c += W1s[t2] * xf[t2];
      d += W3s[t2] * xf[t2];
    }
    xtsv[f] = a; slv[f] = c; xw3[f] = d; resid[f] = xf[15];
#pragma unroll
    for (int o = 0; o < 16; ++o) {
      float acc = 0;
#pragma unroll
      for (int t2 = 0; t2 < 16; ++t2) acc += tws[o * 256 + f * 16 + t2] * xf[t2];
      to[o] += acc;
    }
  }
  size_t o16 = ((size_t)b * Nn + n) * 16;
#pragma unroll
  for (int g = 0; g < 16; ++g) {
    float acc = 0;
#pragma unroll
    for (int k2 = 0; k2 < 16; ++k2) acc += W2s[g * 16 + k2] * xw3[k2];
    srhs[o16 + g] = acc;
  }
#pragma unroll
  for (int i = 0; i < 16; ++i) {
    xts[o16 + i] = xtsv[i];
    slhs[o16 + i] = slv[i];
    base[o16 + i] = to[i] + tbs[i] + resid[i];
  }
}

// ---------------------------------------------------------------------------
// fconv: fp32 -> fp16 bulk convert, same flat layout (for lapH/bsH, 16M elems)
__global__ __launch_bounds__(256) void fconv(
    const float* __restrict__ src, unsigned short* __restrict__ dst) {
  size_t i = ((size_t)blockIdx.x * 256 + threadIdx.x) * 4;
  float4 v = *(const float4*)(src + i);
  u16x4 h;
  h.x = f2h(v.x); h.y = f2h(v.y); h.z = f2h(v.z); h.w = f2h(v.w);
  *(u16x4*)(dst + i) = h;
}

// ---------------------------------------------------------------------------
// vconv2: Vs (4000x4000 fp32) -> Vh (4096x4096 fp16), zero-padded both dims.
__global__ __launch_bounds__(256) void vconv2(
    const float* __restrict__ Vs, unsigned short* __restrict__ Vh) {
  int row = blockIdx.y;
  int col = blockIdx.x * 1024 + threadIdx.x * 4;
  u16x4 h;
  if (row < Nn && col < Nn) {  // col aligned: 4000 % 4 == 0
    float4 v = *(const float4*)(Vs + (size_t)row * Nn + col);
    h.x = f2h(v.x); h.y = f2h(v.y); h.z = f2h(v.z); h.w = f2h(v.w);
  } else {
    h.x = 0; h.y = 0; h.z = 0; h.w = 0;
  }
  *(u16x4*)(Vh + (size_t)row * KS + col) = h;
}

// ---------------------------------------------------------------------------
// tsconv: ts[b][n][f] fp32 -> tsT[(b*16+f)][n] fp16 (B-operand for chebm)
__global__ __launch_bounds__(256) void tsconv(
    const float* __restrict__ ts, unsigned short* __restrict__ tsT) {
  int n = blockIdx.x * 256 + threadIdx.x;
  int col = blockIdx.y;  // 0..63 = (b<<4)|f
  if (n >= Nn) return;
  int b = col >> 4, f = col & 15;
  tsT[(size_t)col * Nn + n] = f2h(ts[((size_t)b * Nn + n) * 16 + f]);
}

// ---------------------------------------------------------------------------
// GEMM1: P[m,k] = sigmoid(slhs[b,m]·srhs[b,k] + bs[m,k]); store P^T fp16
// with row stride KS (pad k-cols left poisoned; they multiply Vh's zero pad).
__global__ __launch_bounds__(256) void gemm1_P(
    const float* __restrict__ slhs, const float* __restrict__ srhs,
    const unsigned short* __restrict__ bsH, unsigned short* __restrict__ PhT, int b) {
  __shared__ float Ms[64][17];
  __shared__ float Cs[64][17];
  __shared__ float Pt[64][65];
  int tid = threadIdx.x;
  int m0 = blockIdx.y * 64, k0 = blockIdx.x * 64;
  int lr = tid >> 2, lq = (tid & 3) << 2;
  {
    int gm = m0 + lr; if (gm > Nn - 1) gm = Nn - 1;
    float4 v = *(const float4*)(slhs + ((size_t)b * Nn + gm) * 16 + lq);
    Ms[lr][lq + 0] = v.x; Ms[lr][lq + 1] = v.y; Ms[lr][lq + 2] = v.z; Ms[lr][lq + 3] = v.w;
    int gk = k0 + lr; if (gk > Nn - 1) gk = Nn - 1;
    float4 w = *(const float4*)(srhs + ((size_t)b * Nn + gk) * 16 + lq);
    Cs[lr][lq + 0] = w.x; Cs[lr][lq + 1] = w.y; Cs[lr][lq + 2] = w.z; Cs[lr][lq + 3] = w.w;
  }
  __syncthreads();
  int tx = tid & 15, ty = tid >> 4;
  float acc[4][4] = {};
#pragma unroll
  for (int f = 0; f < 16; ++f) {
    float a4[4], b4[4];
#pragma unroll
    for (int i = 0; i < 4; ++i) a4[i] = Ms[ty * 4 + i][f];
#pragma unroll
    for (int j = 0; j < 4; ++j) b4[j] = Cs[tx * 4 + j][f];
#pragma unroll
    for (int i = 0; i < 4; ++i)
#pragma unroll
      for (int j = 0; j < 4; ++j) acc[i][j] += a4[i] * b4[j];
  }
#pragma unroll
  for (int i = 0; i < 4; ++i) {
    int m = m0 + ty * 4 + i;
    int k = k0 + tx * 4;
    float bv[4] = {0.f, 0.f, 0.f, 0.f};
    if (m < Nn) {
      if (k + 3 < Nn) {
        u16x4 t4 = *(const u16x4*)(bsH + (size_t)m * Nn + k);
        bv[0] = h2f(t4.x); bv[1] = h2f(t4.y); bv[2] = h2f(t4.z); bv[3] = h2f(t4.w);
      } else {
        for (int j = 0; j < 4; ++j)
          if (k + j < Nn) bv[j] = h2f(bsH[(size_t)m * Nn + k + j]);
      }
    }
#pragma unroll
    for (int j = 0; j < 4; ++j) {
      float z = acc[i][j] + bv[j];
      Pt[ty * 4 + i][tx * 4 + j] = 1.f / (1.f + __expf(-z));
    }
  }
  __syncthreads();
#pragma unroll
  for (int i = 0; i < 4; ++i) {
    int kl = ty * 4 + i;
    int ml = tx * 4;
    int gm = m0 + ml;
    u16x4 h;
    h.x = f2h(Pt[ml + 0][kl]);
    h.y = f2h(Pt[ml + 1][kl]);
    h.z = f2h(Pt[ml + 2][kl]);
    h.w = f2h(Pt[ml + 3][kl]);
    size_t off = (size_t)(k0 + kl) * KS + gm;
    if (gm + 3 < Nn) {
      *(u16x4*)(PhT + off) = h;
    } else {
      unsigned short hv[4] = {h.x, h.y, h.z, h.w};
      for (int q = 0; q < 4; ++q)
        if (gm + q < Nn) PhT[off + q] = hv[q];
    }
  }
}

// ---------------------------------------------------------------------------
// GEMM2, fp16 MFMA, K padded to 4096 (BK=64, no tail), XOR-swizzled LDS.
// Epilogue: SP store + per-row atomicMax (ordered-uint float encoding).
__global__ __launch_bounds__(256) void gemm2_mfma(
    const unsigned short* __restrict__ Vh, const unsigned short* __restrict__ PhT,
    float* __restrict__ SP, unsigned int* __restrict__ rmaxu) {
  __shared__ unsigned short Ah[128 * 64];
  __shared__ unsigned short Bh[128 * 64];
  int t = threadIdx.x;
  int pid = blockIdx.x;
  int pm = (pid & 7) | ((pid >> 8) << 3);
  int pn = (pid >> 3) & 31;
  int row0 = pm * 128, col0 = pn * 128;

  // staging: lane t -> row (t>>3)+p*32, LDS slot (t&7), global oct slot^(row&7)
  // LDS dest p*2048 + t*8 is lane-linear AND equals (row)*64 + slot*8.  [m104]
  int sr = t >> 3, ss = t & 7;
  int soct = ss ^ (sr & 7);
  size_t a_base = (size_t)(row0 + sr) * KS + soct * 8;
  size_t b_base = (size_t)(col0 + sr) * KS + soct * 8;

  int lane = t & 63;
  int wid = t >> 6;
  int wm = (wid >> 1) * 64, wn = (wid & 1) * 64;
  int ml = lane & 15, qd = lane >> 4;

  f32x4 acc[4][4] = {};

  for (int k0 = 0; k0 < KS; k0 += 64) {
#pragma unroll
    for (int p = 0; p < 4; ++p) {
      gld16(Vh + a_base + (size_t)(p * 32) * KS + k0, &Ah[p * 2048 + t * 8]);
      gld16(PhT + b_base + (size_t)(p * 32) * KS + k0, &Bh[p * 2048 + t * 8]);
    }
    __syncthreads();
#pragma unroll
    for (int kk = 0; kk < 2; ++kk) {
      half8 a_h[4], b_h[4];
#pragma unroll
      for (int i = 0; i < 4; ++i) {
        int r = wm + ml + i * 16;
        int slot = (kk * 4 + qd) ^ (r & 7);
        a_h[i] = *(const half8*)&Ah[r * 64 + slot * 8];
      }
#pragma unroll
      for (int j = 0; j < 4; ++j) {
        int r = wn + ml + j * 16;
        int slot = (kk * 4 + qd) ^ (r & 7);
        b_h[j] = *(const half8*)&Bh[r * 64 + slot * 8];
      }
#pragma unroll
      for (int i = 0; i < 4; ++i)
#pragma unroll
        for (int j = 0; j < 4; ++j)
          acc[i][j] = __builtin_amdgcn_mfma_f32_16x16x32_f16(a_h[i], b_h[j], acc[i][j], 0, 0, 0);
    }
    __syncthreads();
  }
  // epilogue: C/D layout col=lane&15, row=(lane>>4)*4+reg [m89]; store + row max
#pragma unroll
  for (int i = 0; i < 4; ++i) {
#pragma unroll
    for (int r = 0; r < 4; ++r) {
      int grow = row0 + wm + i * 16 + qd * 4 + r;
      if (grow >= Nn) continue;
      float rowmax = -3.0e38f;
#pragma unroll
      for (int j = 0; j < 4; ++j) {
        int gcol = col0 + wn + j * 16 + ml;
        if (gcol < Nn) {
          float v = acc[i][j][r];
          SP[(size_t)grow * Nn + gcol] = v;
          rowmax = fmaxf(rowmax, v);
        }
      }
#pragma unroll
      for (int mk = 1; mk < 16; mk <<= 1)
        rowmax = fmaxf(rowmax, __shfl_xor(rowmax, mk, 64));
      if (ml == 0) {
        unsigned u = __float_as_uint(rowmax);
        u = (u & 0x80000000u) ? ~u : (u | 0x80000000u);
        atomicMax(rmaxu + grow, u);
      }
    }
  }
}

// ---------------------------------------------------------------------------
// txsum (split-K): ts0[b,n,f] += sum_{k in chunk} exp(SP-rmax)*xts[b,k,f];
// also accumulates per-row sum-exp into lsum (normalized later by nrm_k).
__global__ __launch_bounds__(256) void txsum_sp(
    const float* __restrict__ SP, const float* __restrict__ xts,
    const unsigned int* __restrict__ rmaxu, float* __restrict__ lsum,
    float* __restrict__ ts0, int b) {
  __shared__ float Ws[16][65];
  __shared__ float Xs[64][17];
  int tid = threadIdx.x;
  int n0 = blockIdx.x * 16;
  int kbase = blockIdx.y * 1000, kend = kbase + 1000;
  int r = tid >> 4, f = tid & 15;
  int lq = f * 4;
  int xr = tid >> 2, xc = (tid & 3) << 2;
  const float* spr = SP + (size_t)(n0 + r) * Nn;
  unsigned u = rmaxu[n0 + r];
  u = (u & 0x80000000u) ? (u ^ 0x80000000u) : ~u;
  float rm = __uint_as_float(u);
  float acc = 0.f, lpart = 0.f;
  for (int k0 = kbase; k0 < kend; k0 += 64) {
    int gx = k0 + xr;
    if (gx < kend) {
      float4 v = *(const float4*)(xts + ((size_t)b * Nn + gx) * 16 + xc);
      Xs[xr][xc + 0] = v.x; Xs[xr][xc + 1] = v.y; Xs[xr][xc + 2] = v.z; Xs[xr][xc + 3] = v.w;
    } else {
      Xs[xr][xc + 0] = 0.f; Xs[xr][xc + 1] = 0.f; Xs[xr][xc + 2] = 0.f; Xs[xr][xc + 3] = 0.f;
    }
    int gk = k0 + lq;
    float4 v = *(const float4*)(spr + gk);  // pad-safe (SP has +4096 floats)
    float e0 = (gk + 0 < kend) ? __expf(v.x - rm) : 0.f;
    float e1 = (gk + 1 < kend) ? __expf(v.y - rm) : 0.f;
    float e2 = (gk + 2 < kend) ? __expf(v.z - rm) : 0.f;
    float e3 = (gk + 3 < kend) ? __expf(v.w - rm) : 0.f;
    Ws[r][lq + 0] = e0; Ws[r][lq + 1] = e1; Ws[r][lq + 2] = e2; Ws[r][lq + 3] = e3;
    lpart += e0 + e1 + e2 + e3;
    __syncthreads();
#pragma unroll
    for (int kk = 0; kk < 64; ++kk) acc += Ws[r][kk] * Xs[kk][f];
    __syncthreads();
  }
#pragma unroll
  for (int mk = 1; mk < 16; mk <<= 1) lpart += __shfl_xor(lpart, mk, 64);
  if (f == 0) atomicAdd(&lsum[n0 + r], lpart);
  atomicAdd(&ts0[((size_t)b * Nn + n0 + r) * 16 + f], acc);
}

// ---------------------------------------------------------------------------
// nrm_k: ts0[b,n,f] /= lsum[b,n]
__global__ __launch_bounds__(256) void nrm_k(
    float* __restrict__ ts0, const float* __restrict__ lsum) {
  int tid = threadIdx.x;
  int b = blockIdx.y;
  int n = blockIdx.x * 16 + (tid >> 4);
  size_t i = ((size_t)b * Nn + n) * 16 + (tid & 15);
  ts0[i] = ts0[i] / lsum[b * Nn + n];
}

// ---------------------------------------------------------------------------
// chebm (MFMA): Cout[(c>>4)*Nn+row][c&15] = scale*sum_k lapH[row][k]*tsT[c][k]
//               - (C0 ? C0 : 0).  K=4000=125*32 exact, no tail.
__global__ __launch_bounds__(256) void chebm(
    const unsigned short* __restrict__ lapH, const unsigned short* __restrict__ tsT,
    const float* __restrict__ C0, float* __restrict__ Cout, float scale) {
  __shared__ unsigned short Ah[64 * 32];
  __shared__ unsigned short Bh[64 * 32];
  int t = threadIdx.x;
  int row0 = blockIdx.x * 64;
  int arow = row0 + (t >> 2); if (arow > Nn - 1) arow = Nn - 1;
  size_t a_base = (size_t)arow * Nn + (t & 3) * 8;
  size_t b_base = (size_t)(t >> 2) * Nn + (t & 3) * 8;

  int lane = t & 63;
  int wid = t >> 6;
  int wm = (wid >> 1) * 32, wn = (wid & 1) * 32;
  int ml = lane & 15, qd = lane >> 4;
  int aoff = (wm + ml) * 32 + qd * 8;
  int boff = (wn + ml) * 32 + qd * 8;

  f32x4 acc[2][2] = {};

  for (int k0 = 0; k0 < Nn; k0 += 32) {
    gld16(lapH + a_base + k0, &Ah[t * 8]);
    gld16(tsT + b_base + k0, &Bh[t * 8]);
    __syncthreads();
    half8 a_h[2], b_h[2];
#pragma unroll
    for (int i = 0; i < 2; ++i) a_h[i] = *(const half8*)&Ah[aoff + i * 512];
#pragma unroll
    for (int j = 0; j < 2; ++j) b_h[j] = *(const half8*)&Bh[boff + j * 512];
#pragma unroll
    for (int i = 0; i < 2; ++i)
#pragma unroll
      for (int j = 0; j < 2; ++j)
        acc[i][j] = __builtin_amdgcn_mfma_f32_16x16x32_f16(a_h[i], b_h[j], acc[i][j], 0, 0, 0);
    __syncthreads();
  }
#pragma unroll
  for (int i = 0; i < 2; ++i)
#pragma unroll
    for (int j = 0; j < 2; ++j) {
      int gcol = wn + j * 16 + ml;
      int b = gcol >> 4, f = gcol & 15;
#pragma unroll
      for (int r = 0; r < 4; ++r) {
        int grow = row0 + wm + i * 16 + qd * 4 + r;
        if (grow < Nn) {
          size_t idx = ((size_t)b * Nn + grow) * 16 + f;
          float v = scale * acc[i][j][r];
          if (C0) v -= C0[idx];
          Cout[idx] = v;
        }
      }
    }
}

// ---------------------------------------------------------------------------
// K_y: y = (1/16)*sum_k sum_f tsk[n,f]*cw[k,f,o] + base ; accumulate LN stats
__global__ __launch_bounds__(256) void ky_k(
    const float* __restrict__ ts0, const float* __restrict__ ts1,
    const float* __restrict__ ts2, const float* __restrict__ cw,
    const float* __restrict__ base, float* __restrict__ ybuf,
    float* __restrict__ lnacc) {
  __shared__ float T0[256], T1[256], T2[256], CW[768];
  __shared__ float rs[256], rq[256];
  int tid = threadIdx.x;
  int b = blockIdx.y;
  size_t base_i = ((size_t)b * Nn + blockIdx.x * 16) * 16;
  T0[tid] = ts0[base_i + tid];
  T1[tid] = ts1[base_i + tid];
  T2[tid] = ts2[base_i + tid];
  for (int i = tid; i < 768; i += 256) CW[i] = cw[i];
  __syncthreads();
  int r = tid >> 4, o = tid & 15;
  float acc = 0.f;
#pragma unroll
  for (int f2 = 0; f2 < 16; ++f2) {
    acc += T0[r * 16 + f2] * CW[f2 * 16 + o];
    acc += T1[r * 16 + f2] * CW[256 + f2 * 16 + o];
    acc += T2[r * 16 + f2] * CW[512 + f2 * 16 + o];
  }
  float y = acc * 0.0625f + base[base_i + tid];
  ybuf[base_i + tid] = y;
  rs[tid] = y; rq[tid] = y * y;
  __syncthreads();
  for (int s2 = 128; s2 > 0; s2 >>= 1) {
    if (tid < s2) { rs[tid] += rs[tid + s2]; rq[tid] += rq[tid + s2]; }
    __syncthreads();
  }
  if (tid == 0) {
    atomicAdd(&lnacc[b * 2 + 0], rs[0]);
    atomicAdd(&lnacc[b * 2 + 1], rq[0]);
  }
}

// ---------------------------------------------------------------------------
// K_ln: layernorm over (N,O) per batch + relu
__global__ __launch_bounds__(256) void kln_k(
    const float* __restrict__ ybuf, const float* __restrict__ lnacc,
    const float* __restrict__ lg, const float* __restrict__ lb,
    float* __restrict__ outp) {
  int tid = threadIdx.x;
  int b = blockIdx.y;
  size_t i = ((size_t)b * Nn + blockIdx.x * 16) * 16 + tid;
  size_t nz = (size_t)blockIdx.x * 256 + tid;
  const float inv = 1.0f / 64000.0f;
  float s = lnacc[b * 2 + 0], q = lnacc[b * 2 + 1];
  float mean = s * inv;
  float var = q * inv - mean * mean;
  float rstd = rsqrtf(var + 1e-5f);
  float v = (ybuf[i] - mean) * rstd * lg[nz] + lb[nz];
  outp[i] = fmaxf(v, 0.f);
}

// ---------------------------------------------------------------------------
extern "C" void kernel_launch(void* const* d_in, const int* in_sizes, int n_in,
                              void* d_out, int out_size, void* d_ws, size_t ws_size,
                              hipStream_t stream) {
  const float* x   = (const float*)d_in[0];
  const float* lap = (const float*)d_in[1];
  const float* W1  = (const float*)d_in[2];
  const float* W2  = (const float*)d_in[3];
  const float* W3  = (const float*)d_in[4];
  const float* bs  = (const float*)d_in[5];
  const float* Vs  = (const float*)d_in[6];
  const float* U1  = (const float*)d_in[7];
  const float* U2  = (const float*)d_in[8];
  const float* U3  = (const float*)d_in[9];
  const float* be  = (const float*)d_in[10];
  const float* Ve  = (const float*)d_in[11];
  const float* cw  = (const float*)d_in[12];
  const float* tw  = (const float*)d_in[13];
  const float* tb  = (const float*)d_in[14];
  const float* lg  = (const float*)d_in[15];
  const float* lb  = (const float*)d_in[16];
  float* ws = (float*)d_ws;
  float* SP = ws;  // NP floats
  unsigned short* Vh   = (unsigned short*)(ws + (size_t)NP);       // 4096*4096
  unsigned short* PhT  = Vh + (size_t)KS * KS;                     // 4096*4096
  unsigned short* lapH = PhT + (size_t)KS * KS;                    // 4000*4000
  unsigned short* bsH  = lapH + (size_t)Nn * Nn;                   // 4000*4000
  unsigned short* tsT  = bsH + (size_t)Nn * Nn;                    // 64*4000
  float* xts  = (float*)(tsT + 64 * Nn + 64);
  float* slhs = xts + 256000;
  float* srhs = slhs + 256000;
  float* base = srhs + 256000;
  float* ts0  = base + 256000;
  float* ts1  = ts0 + 256000;
  float* ts2  = ts1 + 256000;
  float* ybuf = ts2 + 256000;
  float* tl   = ybuf + 256000;  // B*16
  float* tr   = tl + 64;
  float* ecol = tr + 64;
  unsigned int* rmaxu = (unsigned int*)(ecol + 64);  // B*N
  float* lsum = (float*)(rmaxu + Bc * Nn);           // B*N
  float* lnacc = lsum + Bc * Nn;                     // B*2

  hipMemsetAsync(tl, 0, 128 * sizeof(float), stream);
  hipMemsetAsync(lnacc, 0, 8 * sizeof(float), stream);
  hipMemsetAsync(ts0, 0, 256000 * sizeof(float), stream);
  hipMemsetAsync(rmaxu, 0, Bc * Nn * sizeof(unsigned int), stream);
  hipMemsetAsync(lsum, 0, Bc * Nn * sizeof(float), stream);

  k1_trhs<<<dim3(16, 4), 256, 0, stream>>>(x, U1, U2, U3, tl, tr);
  k2_eattn<<<dim3(4), 256, 0, stream>>>(tl, tr, be, Ve, ecol);
  k3_pern<<<dim3(16, 4), 256, 0, stream>>>(x, ecol, W1, W2, W3, tw, tb,
                                           xts, slhs, srhs, base);
  vconv2<<<dim3(4, 4096), 256, 0, stream>>>(Vs, Vh);
  fconv<<<dim3(15625), 256, 0, stream>>>(lap, lapH);
  fconv<<<dim3(15625), 256, 0, stream>>>(bs, bsH);
  for (int b = 0; b < 4; ++b) {
    gemm1_P<<<dim3(63, 63), 256, 0, stream>>>(slhs, srhs, bsH, PhT, b);
    gemm2_mfma<<<dim3(1024), 256, 0, stream>>>(Vh, PhT, SP, rmaxu + b * Nn);
    txsum_sp<<<dim3(250, 4), 256, 0, stream>>>(SP, xts, rmaxu + b * Nn,
                                               lsum + b * Nn, ts0, b);
  }
  nrm_k<<<dim3(250, 4), 256, 0, stream>>>(ts0, lsum);
  tsconv<<<dim3(16, 64), 256, 0, stream>>>(ts0, tsT);
  chebm<<<dim3(63), 256, 0, stream>>>(lapH, tsT, nullptr, ts1, 1.0f);
  tsconv<<<dim3(16, 64), 256, 0, stream>>>(ts1, tsT);
  chebm<<<dim3(63), 256, 0, stream>>>(lapH, tsT, ts0, ts2, 2.0f);
  ky_k<<<dim3(250, 4), 256, 0, stream>>>(ts0, ts1, ts2, cw, base, ybuf, lnacc);
  kln_k<<<dim3(250, 4), 256, 0, stream>>>(ybuf, lnacc, lg, lb, (float*)d_out);
}